// Round 4
// baseline (1806.312 us; speedup 1.0000x reference)
//
#include <hip/hip_runtime.h>
#include <cstdint>
#include <cstddef>

#define HH 128
#define WW 128
#define LL 16384   // HH*WW
#define BL 32768   // B*LL

typedef float  f32x4  __attribute__((ext_vector_type(4)));
typedef short  bf16x8 __attribute__((ext_vector_type(8)));
typedef unsigned short u16x8 __attribute__((ext_vector_type(8)));

static __device__ __forceinline__ unsigned short f2bf(float x) {
  union { float f; unsigned int u; } c; c.f = x;
  unsigned int r = (c.u + 0x7fffu + ((c.u >> 16) & 1u)) >> 16;   // RNE
  return (unsigned short)r;
}
static __device__ __forceinline__ float bflo(unsigned int u) {
  union { unsigned int u; float f; } c; c.u = u << 16; return c.f;
}
static __device__ __forceinline__ float bfhi(unsigned int u) {
  union { unsigned int u; float f; } c; c.u = u & 0xffff0000u; return c.f;
}

// ------------- k0: fold proj into fusion weight; emit B^T bf16 [64][800], kk = t*32+c -
__global__ __launch_bounds__(256) void k_combine(
    const float* __restrict__ proj_w, const float* __restrict__ proj_b,
    const float* __restrict__ fw, const float* __restrict__ fb,
    unsigned short* __restrict__ wctT, float* __restrict__ bc)
{
  if (blockIdx.x == 200) {
    int o = threadIdx.x;
    if (o < 64) {
      float acc = proj_b[o];
      for (int m = 0; m < 64; ++m) acc = fmaf(proj_w[o*64+m], fb[m], acc);
      bc[o] = acc;
    }
    return;
  }
  int gid = blockIdx.x * 256 + threadIdx.x;   // 0..51199 = o*800 + kk
  int o  = gid / 800;
  int kk = gid - o * 800;
  int c  = kk & 31;        // de-interleaved channel (nh*16+d)
  int t  = kk >> 5;        // window position 0..24
  int in = c * 25 + t;     // fusion weight flat index
  float acc = 0.f;
  for (int m = 0; m < 64; ++m) acc = fmaf(proj_w[o*64+m], fw[m*800+in], acc);
  wctT[gid] = f2bf(acc);
}

// ---------------- k1: LayerNorm + QKV, store q/k/v de-interleaved (c' = nh*16 + d) ----
__global__ __launch_bounds__(256) void k_ln_qkv(
    const float* __restrict__ x, const float* __restrict__ qkv_w,
    const float* __restrict__ qkv_b, const float* __restrict__ n1w,
    const float* __restrict__ n1b, float* __restrict__ qo,
    float* __restrict__ ko, float* __restrict__ vo)
{
  __shared__ float sW[96*32];
  __shared__ float sB[96];
  __shared__ float sNw[32], sNb[32];
  for (int i = threadIdx.x; i < 96*32; i += 256) sW[i] = qkv_w[i];
  if (threadIdx.x < 96) sB[threadIdx.x] = qkv_b[threadIdx.x];
  if (threadIdx.x < 32) { sNw[threadIdx.x] = n1w[threadIdx.x]; sNb[threadIdx.x] = n1b[threadIdx.x]; }
  __syncthreads();
  int gid = blockIdx.x * 256 + threadIdx.x;   // 0..BL-1
  int b = gid >> 14, l = gid & (LL - 1);
  const float* xp = x + (size_t)b * 32 * LL + l;
  float xv[32];
  float mean = 0.f;
  #pragma unroll
  for (int c = 0; c < 32; ++c) { xv[c] = xp[(size_t)c * LL]; mean += xv[c]; }
  mean *= 0.03125f;
  float var = 0.f;
  #pragma unroll
  for (int c = 0; c < 32; ++c) { float d = xv[c] - mean; var = fmaf(d, d, var); }
  float rs = rsqrtf(var * 0.03125f + 1e-5f);
  #pragma unroll
  for (int c = 0; c < 32; ++c) xv[c] = (xv[c] - mean) * rs * sNw[c] + sNb[c];
  size_t base = (size_t)gid * 32;
  float* outs[3] = {qo, ko, vo};
  #pragma unroll
  for (int p = 0; p < 3; ++p) {
    float ao[32];
    #pragma unroll
    for (int o = 0; o < 32; ++o) {
      const float* wr = &sW[(p*32 + o) * 32];
      float acc = sB[p*32 + o];
      #pragma unroll
      for (int c = 0; c < 32; ++c) acc = fmaf(xv[c], wr[c], acc);
      ao[(o & 1) * 16 + (o >> 1)] = acc;    // de-interleave heads
    }
    float* op = outs[p] + base;
    #pragma unroll
    for (int e = 0; e < 8; ++e) *(float4*)(op + e*4) = *(const float4*)(&ao[e*4]);
  }
}

// ---------------- k2: tiled windowed attention + fused (fusion∘proj) MFMA GEMM -------
// Block = 4x8 = 32 locations, 256 threads (4 waves).
#define TH 4
#define TW 8
#define NPOS 96   // 8x12 halo
#define KVSTR 40  // bf16 halo row stride in ushorts (80B, 16B-aligned)
#define OSTRU 264 // sO row stride (ushorts): 256 kk + 8 pad
#define SSTR 25   // sS per-thread row stride (dwords, odd -> conflict-free)

#define UNP8(dst, base, U) \
  dst[base+0]=bflo(U.x); dst[base+1]=bfhi(U.x); dst[base+2]=bflo(U.y); dst[base+3]=bfhi(U.y); \
  dst[base+4]=bflo(U.z); dst[base+5]=bfhi(U.z); dst[base+6]=bflo(U.w); dst[base+7]=bfhi(U.w);

#define DOT8(acc, qf, base, U) \
  acc=fmaf(qf[base+0],bflo(U.x),acc); acc=fmaf(qf[base+1],bfhi(U.x),acc); \
  acc=fmaf(qf[base+2],bflo(U.y),acc); acc=fmaf(qf[base+3],bfhi(U.y),acc); \
  acc=fmaf(qf[base+4],bflo(U.z),acc); acc=fmaf(qf[base+5],bfhi(U.z),acc); \
  acc=fmaf(qf[base+6],bflo(U.w),acc); acc=fmaf(qf[base+7],bfhi(U.w),acc);

#define PV8(oo, base, p, U) \
  oo[base+0]=fmaf(p,bflo(U.x),oo[base+0]); oo[base+1]=fmaf(p,bfhi(U.x),oo[base+1]); \
  oo[base+2]=fmaf(p,bflo(U.y),oo[base+2]); oo[base+3]=fmaf(p,bfhi(U.y),oo[base+3]); \
  oo[base+4]=fmaf(p,bflo(U.z),oo[base+4]); oo[base+5]=fmaf(p,bfhi(U.z),oo[base+5]); \
  oo[base+6]=fmaf(p,bflo(U.w),oo[base+6]); oo[base+7]=fmaf(p,bfhi(U.w),oo[base+7]);

__global__ __launch_bounds__(256, 2) void k_attn(
    const float* __restrict__ qi, const float* __restrict__ ki,
    const float* __restrict__ vi, const float* __restrict__ rel_table,
    const unsigned short* __restrict__ wctT, const float* __restrict__ bc,
    float* __restrict__ y2)
{
  __shared__ __align__(16) unsigned short sK[NPOS*KVSTR]; // 7680 B
  __shared__ __align__(16) unsigned short sV[NPOS*KVSTR]; // 7680 B
  __shared__ __align__(16) unsigned short sO[32*OSTRU];   // 16896 B
  __shared__ float sS[256*SSTR];                          // 25600 B
  __shared__ float sRT[162];
  __shared__ float sPar[NPOS];
  // total 58888 B -> 2 blocks/CU

  int tid = threadIdx.x;
  int lane = tid & 63, wv = tid >> 6;
  int b  = blockIdx.z;
  int h0 = blockIdx.y * TH, w0 = blockIdx.x * TW;

  for (int i = tid; i < 162; i += 256) sRT[i] = rel_table[i];
  if (tid < NPOS) {
    int ph = tid / 12, pw = tid - ph * 12;
    int h2 = h0 + ph - 2, w2 = w0 + pw - 2;
    bool valid = ((unsigned)h2 < HH) && ((unsigned)w2 < WW);
    sPar[tid] = (valid && (((h2 + w2) & 1) == 1)) ? 1.f : 0.f;
  }
  // halo staging: K,V fp32->bf16, zero for OOB. 96 pos x 4 chunks x {K,V} = 768 units
  for (int idx = tid; idx < 768; idx += 256) {
    int isv = idx >= 384;
    int rem = idx - (isv ? 384 : 0);
    int pos = rem >> 2, c8 = rem & 3;
    int ph = pos / 12, pw = pos - ph * 12;
    int h2 = h0 + ph - 2, w2 = w0 + pw - 2;
    float4 a = make_float4(0.f,0.f,0.f,0.f), d = a;
    if (((unsigned)h2 < HH) && ((unsigned)w2 < WW)) {
      const float* src = (isv ? vi : ki) + ((size_t)((b << 14) + (h2 << 7) + w2)) * 32 + c8 * 8;
      a = *(const float4*)src;
      d = *(const float4*)(src + 4);
    }
    uint4 pk4;
    pk4.x = (unsigned)f2bf(a.x) | ((unsigned)f2bf(a.y) << 16);
    pk4.y = (unsigned)f2bf(a.z) | ((unsigned)f2bf(a.w) << 16);
    pk4.z = (unsigned)f2bf(d.x) | ((unsigned)f2bf(d.y) << 16);
    pk4.w = (unsigned)f2bf(d.z) | ((unsigned)f2bf(d.w) << 16);
    unsigned short* dp = (isv ? sV : sK) + pos * KVSTR + c8 * 8;
    *(uint4*)dp = pk4;
  }
  __syncthreads();

  f32x4 acc[2] = {{0.f,0.f,0.f,0.f},{0.f,0.f,0.f,0.f}};
  int ocol = wv * 16 + (lane & 15);
  float* srow = &sS[tid * SSTR];

  for (int it = 0; it < 4; ++it) {
    int rest = it * 8 + wv * 2 + (lane >> 5);   // half-wave uniform slot
    if (rest < 26) {
      int nh = rest & 1, r = rest >> 1;         // r 0..12
      int loc = lane & 31;
      int ly = loc >> 3, lx = loc & 7;
      int posb = ly * 12 + lx;
      int nrr = (2*r + 1 < 25) ? 2 : 1;         // wave-uniform
      for (int rr = 0; rr < nrr; ++rr) {
        int tq = 2*r + rr;
        int iq = tq / 5, jq = tq - iq * 5;
        // ---- q row direct from global (fp32), zero if OOB query position
        int hq = h0 + ly + iq - 2, wq = w0 + lx + jq - 2;
        bool vq = ((unsigned)hq < HH) && ((unsigned)wq < WW);
        float parq = (vq && (((hq + wq) & 1) == 1)) ? 1.f : 0.f;
        float qf[16];
        if (vq) {
          const float* qp = qi + ((size_t)((b << 14) + (hq << 7) + wq)) * 32 + nh * 16;
          float4 q0 = *(const float4*)qp;
          float4 q1 = *(const float4*)(qp + 4);
          float4 q2 = *(const float4*)(qp + 8);
          float4 q3 = *(const float4*)(qp + 12);
          qf[0]=q0.x; qf[1]=q0.y; qf[2]=q0.z; qf[3]=q0.w;
          qf[4]=q1.x; qf[5]=q1.y; qf[6]=q1.z; qf[7]=q1.w;
          qf[8]=q2.x; qf[9]=q2.y; qf[10]=q2.z; qf[11]=q2.w;
          qf[12]=q3.x; qf[13]=q3.y; qf[14]=q3.z; qf[15]=q3.w;
        } else {
          #pragma unroll
          for (int e = 0; e < 16; ++e) qf[e] = 0.f;
        }
        // ---- QK^T + bias + mask -> sS, track max
        float mx = -1e30f;
        #pragma unroll
        for (int tk = 0; tk < 25; ++tk) {
          const int ik = tk / 5, jk = tk % 5;
          int pk = posb + ik * 12 + jk;
          const unsigned short* kp = &sK[pk*KVSTR + nh*16];
          uint4 k0 = *(const uint4*)kp;
          uint4 k1 = *(const uint4*)(kp + 8);
          float a0 = 0.f;
          DOT8(a0, qf, 0, k0);
          DOT8(a0, qf, 8, k1);
          float park = sPar[pk];
          float bias = sRT[((iq-ik+4)*9 + (jq-jk+4))*2 + nh];
          float msk = (parq*park == 1.f) ? 0.f : -100.f;
          float sc = fmaf(a0, 0.25f, bias) + msk;
          srow[tk] = sc;
          mx = fmaxf(mx, sc);
        }
        // ---- softmax: exp + sum (write exp back)
        float sum = 0.f;
        #pragma unroll
        for (int tk = 0; tk < 25; ++tk) {
          float e0 = __expf(srow[tk] - mx);
          srow[tk] = e0;
          sum += e0;
        }
        float inv = 1.f / sum;
        // ---- PV
        float oo[16];
        #pragma unroll
        for (int e = 0; e < 16; ++e) oo[e] = 0.f;
        #pragma unroll
        for (int tk = 0; tk < 25; ++tk) {
          const int ik = tk / 5, jk = tk % 5;
          int pk = posb + ik * 12 + jk;
          float p = srow[tk] * inv;
          const unsigned short* vp = &sV[pk*KVSTR + nh*16];
          uint4 v0 = *(const uint4*)vp;
          uint4 v1 = *(const uint4*)(vp + 8);
          PV8(oo, 0, p, v0);
          PV8(oo, 8, p, v1);
        }
        // ---- write O row (bf16) to sO, kk_local = (tq - it*8)*32 + nh*16
        int kl0 = (tq - it*8) * 32 + nh * 16;
        uint4 w0;
        w0.x = (unsigned)f2bf(oo[0]) | ((unsigned)f2bf(oo[1]) << 16);
        w0.y = (unsigned)f2bf(oo[2]) | ((unsigned)f2bf(oo[3]) << 16);
        w0.z = (unsigned)f2bf(oo[4]) | ((unsigned)f2bf(oo[5]) << 16);
        w0.w = (unsigned)f2bf(oo[6]) | ((unsigned)f2bf(oo[7]) << 16);
        *(uint4*)&sO[loc*OSTRU + kl0] = w0;
        w0.x = (unsigned)f2bf(oo[8])  | ((unsigned)f2bf(oo[9])  << 16);
        w0.y = (unsigned)f2bf(oo[10]) | ((unsigned)f2bf(oo[11]) << 16);
        w0.z = (unsigned)f2bf(oo[12]) | ((unsigned)f2bf(oo[13]) << 16);
        w0.w = (unsigned)f2bf(oo[14]) | ((unsigned)f2bf(oo[15]) << 16);
        *(uint4*)&sO[loc*OSTRU + kl0 + 8] = w0;
      }
    }
    __syncthreads();
    // MFMA phase: K-chunk [it*256, it*256 + nk*32)
    int nk = (it < 3) ? 8 : 1;
    const unsigned short* bcol = wctT + (size_t)ocol * 800 + it * 256 + (lane >> 4) * 8;
    for (int kt = 0; kt < nk; ++kt) {
      bf16x8 bfrag = *(const bf16x8*)(bcol + kt * 32);
      #pragma unroll
      for (int mt = 0; mt < 2; ++mt) {
        bf16x8 afrag = *(const bf16x8*)&sO[(mt*16 + (lane & 15))*OSTRU + kt*32 + (lane >> 4)*8];
        acc[mt] = __builtin_amdgcn_mfma_f32_16x16x32_bf16(afrag, bfrag, acc[mt], 0, 0, 0);
      }
    }
    __syncthreads();
  }
  // epilogue: y2[loc][o] = acc + bc[o]
  float bco = bc[ocol];
  #pragma unroll
  for (int mt = 0; mt < 2; ++mt) {
    #pragma unroll
    for (int r2 = 0; r2 < 4; ++r2) {
      int loc = mt * 16 + (lane >> 4) * 4 + r2;
      int ly = loc >> 3, lx = loc & 7;
      int gid = (b << 14) + ((h0 + ly) << 7) + (w0 + lx);
      y2[(size_t)gid * 64 + ocol] = acc[mt][r2] + bco;
    }
  }
}

// ---------------- k3: LN + MLP(GELU exact) + residual + transpose store --------------
__global__ __launch_bounds__(128, 1) void k_mlp(
    const float* __restrict__ y2, const float* __restrict__ n2w,
    const float* __restrict__ n2b, const float* __restrict__ w1,
    const float* __restrict__ b1, const float* __restrict__ w2,
    const float* __restrict__ b2, float* __restrict__ out)
{
  __shared__ __align__(16) float sW1[128*64];
  __shared__ __align__(16) float sW2[64*128];
  __shared__ float sNw[64], sNb[64], sB1[128], sB2[64];
  int tid = threadIdx.x;
  for (int i = tid; i < 128*64; i += 128) sW1[i] = w1[i];
  for (int i = tid; i < 64*128; i += 128) sW2[i] = w2[i];
  if (tid < 64) { sNw[tid] = n2w[tid]; sNb[tid] = n2b[tid]; sB2[tid] = b2[tid]; }
  sB1[tid] = b1[tid];
  __syncthreads();
  int gid = blockIdx.x * 128 + tid;
  int b = gid >> 14, l = gid & (LL - 1);
  float yv[64], hn[64], macc[64];
  const float* yp = y2 + (size_t)gid * 64;
  float mean = 0.f;
  #pragma unroll
  for (int c = 0; c < 64; ++c) { yv[c] = yp[c]; mean += yv[c]; }
  mean *= (1.f/64.f);
  float var = 0.f;
  #pragma unroll
  for (int c = 0; c < 64; ++c) { float d = yv[c] - mean; var = fmaf(d, d, var); }
  float rs = rsqrtf(var * (1.f/64.f) + 1e-5f);
  #pragma unroll
  for (int c = 0; c < 64; ++c) hn[c] = (yv[c] - mean) * rs * sNw[c] + sNb[c];
  #pragma unroll
  for (int o = 0; o < 64; ++o) macc[o] = sB2[o];
  for (int j4 = 0; j4 < 32; ++j4) {
    float g[4];
    #pragma unroll
    for (int u = 0; u < 4; ++u) {
      int j = j4*4 + u;
      const float* wr = &sW1[j*64];
      float hj = sB1[j];
      #pragma unroll
      for (int c = 0; c < 64; ++c) hj = fmaf(hn[c], wr[c], hj);
      g[u] = 0.5f * hj * (1.f + erff(hj * 0.70710678118f));
    }
    #pragma unroll
    for (int o = 0; o < 64; ++o) {
      const float4 w4 = *(const float4*)(&sW2[o*128 + j4*4]);
      macc[o] = fmaf(g[0], w4.x, fmaf(g[1], w4.y, fmaf(g[2], w4.z, fmaf(g[3], w4.w, macc[o]))));
    }
  }
  size_t ob = (size_t)b * 64 * LL + l;
  #pragma unroll
  for (int o = 0; o < 64; ++o) out[ob + (size_t)o * LL] = yv[o] + macc[o];
}

extern "C" void kernel_launch(void* const* d_in, const int* in_sizes, int n_in,
                              void* d_out, int out_size, void* d_ws, size_t ws_size,
                              hipStream_t stream) {
  const float* x         = (const float*)d_in[0];
  const float* qkv_w     = (const float*)d_in[1];
  const float* qkv_b     = (const float*)d_in[2];
  const float* rel_table = (const float*)d_in[3];
  const float* n1w       = (const float*)d_in[4];
  const float* n1b       = (const float*)d_in[5];
  const float* n2w       = (const float*)d_in[6];
  const float* n2b       = (const float*)d_in[7];
  const float* proj_w    = (const float*)d_in[8];
  const float* proj_b    = (const float*)d_in[9];
  const float* fw        = (const float*)d_in[10];
  const float* fb        = (const float*)d_in[11];
  const float* w1        = (const float*)d_in[12];
  const float* b1        = (const float*)d_in[13];
  const float* w2        = (const float*)d_in[14];
  const float* b2        = (const float*)d_in[15];

  float* ws  = (float*)d_ws;
  float* q   = ws;                       // BL*32 floats
  float* k   = ws + 1048576;
  float* v   = ws + 2097152;
  float* y2  = ws + 3145728;             // BL*64 floats
  unsigned short* wctT = (unsigned short*)(ws + 5242880);  // 64*800 bf16
  float* bc  = ws + 5268480;             // 64 floats
  float* out = (float*)d_out;

  k_combine<<<201, 256, 0, stream>>>(proj_w, proj_b, fw, fb, wctT, bc);
  k_ln_qkv<<<128, 256, 0, stream>>>(x, qkv_w, qkv_b, n1w, n1b, q, k, v);
  k_attn<<<dim3(WW/TW, HH/TH, 2), 256, 0, stream>>>(q, k, v, rel_table, wctT, bc, y2);
  k_mlp<<<256, 128, 0, stream>>>(y2, n2w, n2b, w1, b1, w2, b2, out);
}

// Round 5
// 246.698 us; speedup vs baseline: 7.3219x; 7.3219x over previous
//
#include <hip/hip_runtime.h>
#include <cstdint>
#include <cstddef>

#define HH 128
#define WW 128
#define LL 16384   // HH*WW
#define BL 32768   // B*LL

typedef float  f32x4  __attribute__((ext_vector_type(4)));
typedef short  bf16x8 __attribute__((ext_vector_type(8)));

static __device__ __forceinline__ unsigned short f2bf(float x) {
  union { float f; unsigned int u; } c; c.f = x;
  unsigned int r = (c.u + 0x7fffu + ((c.u >> 16) & 1u)) >> 16;   // RNE
  return (unsigned short)r;
}
static __device__ __forceinline__ float bflo(unsigned int u) {
  union { unsigned int u; float f; } c; c.u = u << 16; return c.f;
}
static __device__ __forceinline__ float bfhi(unsigned int u) {
  union { unsigned int u; float f; } c; c.u = u & 0xffff0000u; return c.f;
}

// ------------- k0: fold proj into fusion weight; emit B^T bf16 [64][800], kk = t*32+c -
__global__ __launch_bounds__(256) void k_combine(
    const float* __restrict__ proj_w, const float* __restrict__ proj_b,
    const float* __restrict__ fw, const float* __restrict__ fb,
    unsigned short* __restrict__ wctT, float* __restrict__ bc)
{
  if (blockIdx.x == 200) {
    int o = threadIdx.x;
    if (o < 64) {
      float acc = proj_b[o];
      for (int m = 0; m < 64; ++m) acc = fmaf(proj_w[o*64+m], fb[m], acc);
      bc[o] = acc;
    }
    return;
  }
  int gid = blockIdx.x * 256 + threadIdx.x;   // 0..51199 = o*800 + kk
  int o  = gid / 800;
  int kk = gid - o * 800;
  int c  = kk & 31;        // de-interleaved channel (nh*16+d)
  int t  = kk >> 5;        // window position 0..24
  int in = c * 25 + t;     // fusion weight flat index
  float acc = 0.f;
  for (int m = 0; m < 64; ++m) acc = fmaf(proj_w[o*64+m], fw[m*800+in], acc);
  wctT[gid] = f2bf(acc);
}

// ---------------- k1: LayerNorm + QKV, store q/k/v de-interleaved (c' = nh*16 + d) ----
__global__ __launch_bounds__(128) void k_ln_qkv(
    const float* __restrict__ x, const float* __restrict__ qkv_w,
    const float* __restrict__ qkv_b, const float* __restrict__ n1w,
    const float* __restrict__ n1b, float* __restrict__ qo,
    float* __restrict__ ko, float* __restrict__ vo)
{
  __shared__ float sW[96*32];
  __shared__ float sB[96];
  __shared__ float sNw[32], sNb[32];
  for (int i = threadIdx.x; i < 96*32; i += 128) sW[i] = qkv_w[i];
  if (threadIdx.x < 96) sB[threadIdx.x] = qkv_b[threadIdx.x];
  if (threadIdx.x < 32) { sNw[threadIdx.x] = n1w[threadIdx.x]; sNb[threadIdx.x] = n1b[threadIdx.x]; }
  __syncthreads();
  int gid = blockIdx.x * 128 + threadIdx.x;   // 0..BL-1
  int b = gid >> 14, l = gid & (LL - 1);
  const float* xp = x + (size_t)b * 32 * LL + l;
  float xv[32];
  float mean = 0.f;
  #pragma unroll
  for (int c = 0; c < 32; ++c) { xv[c] = xp[(size_t)c * LL]; mean += xv[c]; }
  mean *= 0.03125f;
  float var = 0.f;
  #pragma unroll
  for (int c = 0; c < 32; ++c) { float d = xv[c] - mean; var = fmaf(d, d, var); }
  float rs = rsqrtf(var * 0.03125f + 1e-5f);
  #pragma unroll
  for (int c = 0; c < 32; ++c) xv[c] = (xv[c] - mean) * rs * sNw[c] + sNb[c];
  size_t base = (size_t)gid * 32;
  float* outs[3] = {qo, ko, vo};
  #pragma unroll
  for (int p = 0; p < 3; ++p) {
    float ao[32];
    #pragma unroll
    for (int o = 0; o < 32; ++o) {
      const float* wr = &sW[(p*32 + o) * 32];
      float acc = sB[p*32 + o];
      #pragma unroll
      for (int c = 0; c < 32; ++c) acc = fmaf(xv[c], wr[c], acc);
      ao[(o & 1) * 16 + (o >> 1)] = acc;    // de-interleave heads
    }
    float* op = outs[p] + base;
    #pragma unroll
    for (int e = 0; e < 8; ++e) *(float4*)(op + e*4) = *(const float4*)(&ao[e*4]);
  }
}

// ---------------- k2: tiled windowed attention + fused (fusion∘proj) MFMA GEMM -------
// Block = 4x8 = 32 locations, 256 threads (4 waves). 7 phases x 4 tq.
#define TH 4
#define TW 8
#define NPOS 96   // 8x12 halo
#define KVSTR 40  // bf16 halo row stride in ushorts (80B, 16B-aligned)
#define OSTRU 136 // sO row stride (ushorts): 128 kk + 8 pad (272B, 16B-aligned)

#define UNP8(dst, base, U) \
  dst[base+0]=bflo(U.x); dst[base+1]=bfhi(U.x); dst[base+2]=bflo(U.y); dst[base+3]=bfhi(U.y); \
  dst[base+4]=bflo(U.z); dst[base+5]=bfhi(U.z); dst[base+6]=bflo(U.w); dst[base+7]=bfhi(U.w);

#define DOT8(acc, qf, base, U) \
  acc=fmaf(qf[base+0],bflo(U.x),acc); acc=fmaf(qf[base+1],bfhi(U.x),acc); \
  acc=fmaf(qf[base+2],bflo(U.y),acc); acc=fmaf(qf[base+3],bfhi(U.y),acc); \
  acc=fmaf(qf[base+4],bflo(U.z),acc); acc=fmaf(qf[base+5],bfhi(U.z),acc); \
  acc=fmaf(qf[base+6],bflo(U.w),acc); acc=fmaf(qf[base+7],bfhi(U.w),acc);

#define PV8(oo, base, p, U) \
  oo[base+0]=fmaf(p,bflo(U.x),oo[base+0]); oo[base+1]=fmaf(p,bfhi(U.x),oo[base+1]); \
  oo[base+2]=fmaf(p,bflo(U.y),oo[base+2]); oo[base+3]=fmaf(p,bfhi(U.y),oo[base+3]); \
  oo[base+4]=fmaf(p,bflo(U.z),oo[base+4]); oo[base+5]=fmaf(p,bfhi(U.z),oo[base+5]); \
  oo[base+6]=fmaf(p,bflo(U.w),oo[base+6]); oo[base+7]=fmaf(p,bfhi(U.w),oo[base+7]);

__global__ __launch_bounds__(256, 2) void k_attn(
    const float* __restrict__ qi, const float* __restrict__ ki,
    const float* __restrict__ vi, const float* __restrict__ rel_table,
    const unsigned short* __restrict__ wctT, const float* __restrict__ bc,
    float* __restrict__ y2)
{
  __shared__ __align__(16) unsigned short sQ[NPOS*KVSTR]; // 7680 B
  __shared__ __align__(16) unsigned short sK[NPOS*KVSTR]; // 7680 B
  __shared__ __align__(16) unsigned short sV[NPOS*KVSTR]; // 7680 B
  __shared__ __align__(16) unsigned short sO[32*OSTRU];   // 8704 B
  __shared__ float sS[256*25];                            // 25600 B
  __shared__ float sRT[162];
  __shared__ float sPar[NPOS];
  // total 58376 B -> 2 blocks/CU

  int tid = threadIdx.x;
  int lane = tid & 63, wv = tid >> 6;
  int b  = blockIdx.z;
  int h0 = blockIdx.y * TH, w0 = blockIdx.x * TW;

  for (int i = tid; i < 162; i += 256) sRT[i] = rel_table[i];
  if (tid < NPOS) {
    int ph = tid / 12, pw = tid - ph * 12;
    int h2 = h0 + ph - 2, w2 = w0 + pw - 2;
    bool valid = ((unsigned)h2 < HH) && ((unsigned)w2 < WW);
    sPar[tid] = (valid && (((h2 + w2) & 1) == 1)) ? 1.f : 0.f;
  }
  // halo staging: K,V,Q fp32->bf16, zero for OOB. 3 arrays x 96 pos x 4 chunks = 1152
  for (int idx = tid; idx < 1152; idx += 256) {
    int arr = idx / 384;                  // 0=K, 1=V, 2=Q
    int rem = idx - arr * 384;
    int pos = rem >> 2, c8 = rem & 3;
    int ph = pos / 12, pw = pos - ph * 12;
    int h2 = h0 + ph - 2, w2 = w0 + pw - 2;
    float4 a = make_float4(0.f,0.f,0.f,0.f), d = a;
    if (((unsigned)h2 < HH) && ((unsigned)w2 < WW)) {
      const float* src = (arr == 0 ? ki : arr == 1 ? vi : qi)
                       + ((size_t)((b << 14) + (h2 << 7) + w2)) * 32 + c8 * 8;
      a = *(const float4*)src;
      d = *(const float4*)(src + 4);
    }
    uint4 pk4;
    pk4.x = (unsigned)f2bf(a.x) | ((unsigned)f2bf(a.y) << 16);
    pk4.y = (unsigned)f2bf(a.z) | ((unsigned)f2bf(a.w) << 16);
    pk4.z = (unsigned)f2bf(d.x) | ((unsigned)f2bf(d.y) << 16);
    pk4.w = (unsigned)f2bf(d.z) | ((unsigned)f2bf(d.w) << 16);
    unsigned short* dp = (arr == 0 ? sK : arr == 1 ? sV : sQ) + pos * KVSTR + c8 * 8;
    *(uint4*)dp = pk4;
  }
  __syncthreads();

  f32x4 acc[2] = {{0.f,0.f,0.f,0.f},{0.f,0.f,0.f,0.f}};
  int ocol = wv * 16 + (lane & 15);
  float* srow = &sS[tid * 25];

  for (int it = 0; it < 7; ++it) {
    int rest = it * 8 + wv * 2 + (lane >> 5);   // half-wave-uniform slot; one row/thread
    if (rest < 50) {
      int nh = rest & 1, tq = rest >> 1;        // tq in [it*4, it*4+4)
      int loc = lane & 31;
      int ly = loc >> 3, lx = loc & 7;
      int posb = ly * 12 + lx;
      int iq = tq / 5, jq = tq - iq * 5;
      int pq = posb + iq * 12 + jq;
      float parq = sPar[pq];
      float qf[16];
      {
        const unsigned short* qp = &sQ[pq*KVSTR + nh*16];
        uint4 q0 = *(const uint4*)qp;
        uint4 q1 = *(const uint4*)(qp + 8);
        UNP8(qf, 0, q0);
        UNP8(qf, 8, q1);
      }
      // ---- QK^T + bias + mask -> srow (LDS), track max. Outer loop ROLLED.
      float mx = -1e30f;
      #pragma unroll 1
      for (int ik = 0; ik < 5; ++ik) {
        int pkrow = posb + ik * 12;
        int rrow = (iq - ik + 4) * 9 + jq + 4;
        #pragma unroll
        for (int jk = 0; jk < 5; ++jk) {
          int pk = pkrow + jk;
          const unsigned short* kp = &sK[pk*KVSTR + nh*16];
          uint4 k0 = *(const uint4*)kp;
          uint4 k1 = *(const uint4*)(kp + 8);
          float a0 = 0.f;
          DOT8(a0, qf, 0, k0);
          DOT8(a0, qf, 8, k1);
          float park = sPar[pk];
          float bias = sRT[(rrow - jk) * 2 + nh];
          float msk = (parq * park == 1.f) ? 0.f : -100.f;
          float sc = fmaf(a0, 0.25f, bias) + msk;
          srow[ik*5 + jk] = sc;
          mx = fmaxf(mx, sc);
        }
      }
      // ---- softmax: exp + sum (write exp back)
      float sum = 0.f;
      #pragma unroll 1
      for (int tk = 0; tk < 25; ++tk) {
        float e0 = __expf(srow[tk] - mx);
        srow[tk] = e0;
        sum += e0;
      }
      float inv = 1.f / sum;
      // ---- PV. Outer loop ROLLED.
      float oo[16];
      #pragma unroll
      for (int e = 0; e < 16; ++e) oo[e] = 0.f;
      #pragma unroll 1
      for (int ik = 0; ik < 5; ++ik) {
        int pkrow = posb + ik * 12;
        #pragma unroll
        for (int jk = 0; jk < 5; ++jk) {
          int pk = pkrow + jk;
          float p = srow[ik*5 + jk] * inv;
          const unsigned short* vp = &sV[pk*KVSTR + nh*16];
          uint4 v0 = *(const uint4*)vp;
          uint4 v1 = *(const uint4*)(vp + 8);
          PV8(oo, 0, p, v0);
          PV8(oo, 8, p, v1);
        }
      }
      // ---- write O row (bf16) to sO, kk_local = (tq - it*4)*32 + nh*16
      int kl0 = (tq - it*4) * 32 + nh * 16;
      uint4 w0;
      w0.x = (unsigned)f2bf(oo[0]) | ((unsigned)f2bf(oo[1]) << 16);
      w0.y = (unsigned)f2bf(oo[2]) | ((unsigned)f2bf(oo[3]) << 16);
      w0.z = (unsigned)f2bf(oo[4]) | ((unsigned)f2bf(oo[5]) << 16);
      w0.w = (unsigned)f2bf(oo[6]) | ((unsigned)f2bf(oo[7]) << 16);
      *(uint4*)&sO[loc*OSTRU + kl0] = w0;
      w0.x = (unsigned)f2bf(oo[8])  | ((unsigned)f2bf(oo[9])  << 16);
      w0.y = (unsigned)f2bf(oo[10]) | ((unsigned)f2bf(oo[11]) << 16);
      w0.z = (unsigned)f2bf(oo[12]) | ((unsigned)f2bf(oo[13]) << 16);
      w0.w = (unsigned)f2bf(oo[14]) | ((unsigned)f2bf(oo[15]) << 16);
      *(uint4*)&sO[loc*OSTRU + kl0 + 8] = w0;
    }
    __syncthreads();
    // MFMA phase: K-chunk [it*128, it*128 + nk*32)
    int nk = (it < 6) ? 4 : 1;
    const unsigned short* bcol = wctT + (size_t)ocol * 800 + it * 128 + (lane >> 4) * 8;
    for (int kt = 0; kt < nk; ++kt) {
      bf16x8 bfrag = *(const bf16x8*)(bcol + kt * 32);
      #pragma unroll
      for (int mt = 0; mt < 2; ++mt) {
        bf16x8 afrag = *(const bf16x8*)&sO[(mt*16 + (lane & 15))*OSTRU + kt*32 + (lane >> 4)*8];
        acc[mt] = __builtin_amdgcn_mfma_f32_16x16x32_bf16(afrag, bfrag, acc[mt], 0, 0, 0);
      }
    }
    __syncthreads();
  }
  // epilogue: y2[loc][o] = acc + bc[o]
  float bco = bc[ocol];
  #pragma unroll
  for (int mt = 0; mt < 2; ++mt) {
    #pragma unroll
    for (int r2 = 0; r2 < 4; ++r2) {
      int loc = mt * 16 + (lane >> 4) * 4 + r2;
      int ly = loc >> 3, lx = loc & 7;
      int gid = (b << 14) + ((h0 + ly) << 7) + (w0 + lx);
      y2[(size_t)gid * 64 + ocol] = acc[mt][r2] + bco;
    }
  }
}

// ---------------- k3: LN + MLP(GELU exact) + residual + transpose store --------------
__global__ __launch_bounds__(128, 1) void k_mlp(
    const float* __restrict__ y2, const float* __restrict__ n2w,
    const float* __restrict__ n2b, const float* __restrict__ w1,
    const float* __restrict__ b1, const float* __restrict__ w2,
    const float* __restrict__ b2, float* __restrict__ out)
{
  __shared__ __align__(16) float sW1[128*64];
  __shared__ __align__(16) float sW2[64*128];
  __shared__ float sNw[64], sNb[64], sB1[128], sB2[64];
  int tid = threadIdx.x;
  for (int i = tid; i < 128*64; i += 128) sW1[i] = w1[i];
  for (int i = tid; i < 64*128; i += 128) sW2[i] = w2[i];
  if (tid < 64) { sNw[tid] = n2w[tid]; sNb[tid] = n2b[tid]; sB2[tid] = b2[tid]; }
  sB1[tid] = b1[tid];
  __syncthreads();
  int gid = blockIdx.x * 128 + tid;
  int b = gid >> 14, l = gid & (LL - 1);
  float yv[64], hn[64], macc[64];
  const float* yp = y2 + (size_t)gid * 64;
  float mean = 0.f;
  #pragma unroll
  for (int c = 0; c < 64; ++c) { yv[c] = yp[c]; mean += yv[c]; }
  mean *= (1.f/64.f);
  float var = 0.f;
  #pragma unroll
  for (int c = 0; c < 64; ++c) { float d = yv[c] - mean; var = fmaf(d, d, var); }
  float rs = rsqrtf(var * (1.f/64.f) + 1e-5f);
  #pragma unroll
  for (int c = 0; c < 64; ++c) hn[c] = (yv[c] - mean) * rs * sNw[c] + sNb[c];
  #pragma unroll
  for (int o = 0; o < 64; ++o) macc[o] = sB2[o];
  for (int j4 = 0; j4 < 32; ++j4) {
    float g[4];
    #pragma unroll
    for (int u = 0; u < 4; ++u) {
      int j = j4*4 + u;
      const float* wr = &sW1[j*64];
      float hj = sB1[j];
      #pragma unroll
      for (int c = 0; c < 64; ++c) hj = fmaf(hn[c], wr[c], hj);
      g[u] = 0.5f * hj * (1.f + erff(hj * 0.70710678118f));
    }
    #pragma unroll
    for (int o = 0; o < 64; ++o) {
      const float4 w4 = *(const float4*)(&sW2[o*128 + j4*4]);
      macc[o] = fmaf(g[0], w4.x, fmaf(g[1], w4.y, fmaf(g[2], w4.z, fmaf(g[3], w4.w, macc[o]))));
    }
  }
  size_t ob = (size_t)b * 64 * LL + l;
  #pragma unroll
  for (int o = 0; o < 64; ++o) out[ob + (size_t)o * LL] = yv[o] + macc[o];
}

extern "C" void kernel_launch(void* const* d_in, const int* in_sizes, int n_in,
                              void* d_out, int out_size, void* d_ws, size_t ws_size,
                              hipStream_t stream) {
  const float* x         = (const float*)d_in[0];
  const float* qkv_w     = (const float*)d_in[1];
  const float* qkv_b     = (const float*)d_in[2];
  const float* rel_table = (const float*)d_in[3];
  const float* n1w       = (const float*)d_in[4];
  const float* n1b       = (const float*)d_in[5];
  const float* n2w       = (const float*)d_in[6];
  const float* n2b       = (const float*)d_in[7];
  const float* proj_w    = (const float*)d_in[8];
  const float* proj_b    = (const float*)d_in[9];
  const float* fw        = (const float*)d_in[10];
  const float* fb        = (const float*)d_in[11];
  const float* w1        = (const float*)d_in[12];
  const float* b1        = (const float*)d_in[13];
  const float* w2        = (const float*)d_in[14];
  const float* b2        = (const float*)d_in[15];

  float* ws  = (float*)d_ws;
  float* q   = ws;                       // BL*32 floats
  float* k   = ws + 1048576;
  float* v   = ws + 2097152;
  float* y2  = ws + 3145728;             // BL*64 floats
  unsigned short* wctT = (unsigned short*)(ws + 5242880);  // 64*800 bf16
  float* bc  = ws + 5268480;             // 64 floats
  float* out = (float*)d_out;

  k_combine<<<201, 256, 0, stream>>>(proj_w, proj_b, fw, fb, wctT, bc);
  k_ln_qkv<<<256, 128, 0, stream>>>(x, qkv_w, qkv_b, n1w, n1b, q, k, v);
  k_attn<<<dim3(WW/TW, HH/TH, 2), 256, 0, stream>>>(q, k, v, rel_table, wctT, bc, y2);
  k_mlp<<<256, 128, 0, stream>>>(y2, n2w, n2b, w1, b1, w2, b2, out);
}

// Round 6
// 115.444 us; speedup vs baseline: 15.6466x; 2.1369x over previous
//
#include <hip/hip_runtime.h>
#include <cstdint>
#include <cstddef>

#define HH 128
#define WW 128
#define LL 16384   // HH*WW
#define BL 32768   // B*LL

typedef float  f32x4  __attribute__((ext_vector_type(4)));
typedef short  bf16x8 __attribute__((ext_vector_type(8)));

static __device__ __forceinline__ unsigned short f2bf(float x) {
  union { float f; unsigned int u; } c; c.f = x;
  unsigned int r = (c.u + 0x7fffu + ((c.u >> 16) & 1u)) >> 16;   // RNE
  return (unsigned short)r;
}
static __device__ __forceinline__ float bflo(unsigned int u) {
  union { unsigned int u; float f; } c; c.u = u << 16; return c.f;
}
static __device__ __forceinline__ float bfhi(unsigned int u) {
  union { unsigned int u; float f; } c; c.u = u & 0xffff0000u; return c.f;
}

// ---- k0: fold proj into fusion weight (bf16 B^T [64][800], kk = t*32+c); cast w1/w2 --
__global__ __launch_bounds__(256) void k_combine(
    const float* __restrict__ proj_w, const float* __restrict__ proj_b,
    const float* __restrict__ fw, const float* __restrict__ fb,
    const float* __restrict__ w1, const float* __restrict__ w2,
    unsigned short* __restrict__ wctT, float* __restrict__ bc,
    unsigned short* __restrict__ w1b, unsigned short* __restrict__ w2b)
{
  if (blockIdx.x == 200) {
    int o = threadIdx.x;
    if (o < 64) {
      float acc = proj_b[o];
      for (int m = 0; m < 64; ++m) acc = fmaf(proj_w[o*64+m], fb[m], acc);
      bc[o] = acc;
    }
    return;
  }
  if (blockIdx.x == 201) {
    for (int i = threadIdx.x; i < 8192; i += 256) w1b[i] = f2bf(w1[i]);
    return;
  }
  if (blockIdx.x == 202) {
    for (int i = threadIdx.x; i < 8192; i += 256) w2b[i] = f2bf(w2[i]);
    return;
  }
  int gid = blockIdx.x * 256 + threadIdx.x;   // 0..51199 = o*800 + kk
  int o  = gid / 800;
  int kk = gid - o * 800;
  int c  = kk & 31;        // de-interleaved channel (nh*16+d)
  int t  = kk >> 5;        // window position 0..24
  int in = c * 25 + t;     // fusion weight flat index
  float acc = 0.f;
  for (int m = 0; m < 64; ++m) acc = fmaf(proj_w[o*64+m], fw[m*800+in], acc);
  wctT[gid] = f2bf(acc);
}

// ---- k1: LayerNorm + QKV, bf16 out, de-interleaved (c' = nh*16 + d); 3-way split ----
__global__ __launch_bounds__(128) void k_ln_qkv(
    const float* __restrict__ x, const float* __restrict__ qkv_w,
    const float* __restrict__ qkv_b, const float* __restrict__ n1w,
    const float* __restrict__ n1b, unsigned short* __restrict__ qo,
    unsigned short* __restrict__ ko, unsigned short* __restrict__ vo)
{
  __shared__ float sW[32*32];
  __shared__ float sB[32];
  __shared__ float sNw[32], sNb[32];
  int p = blockIdx.y;                         // 0=q 1=k 2=v
  for (int i = threadIdx.x; i < 32*32; i += 128) sW[i] = qkv_w[p*1024 + i];
  if (threadIdx.x < 32) {
    sB[threadIdx.x]  = qkv_b[p*32 + threadIdx.x];
    sNw[threadIdx.x] = n1w[threadIdx.x];
    sNb[threadIdx.x] = n1b[threadIdx.x];
  }
  __syncthreads();
  int gid = blockIdx.x * 128 + threadIdx.x;   // 0..BL-1
  int b = gid >> 14, l = gid & (LL - 1);
  const float* xp = x + (size_t)b * 32 * LL + l;
  float xv[32];
  float mean = 0.f;
  #pragma unroll
  for (int c = 0; c < 32; ++c) { xv[c] = xp[(size_t)c * LL]; mean += xv[c]; }
  mean *= 0.03125f;
  float var = 0.f;
  #pragma unroll
  for (int c = 0; c < 32; ++c) { float d = xv[c] - mean; var = fmaf(d, d, var); }
  float rs = rsqrtf(var * 0.03125f + 1e-5f);
  #pragma unroll
  for (int c = 0; c < 32; ++c) xv[c] = (xv[c] - mean) * rs * sNw[c] + sNb[c];
  float ao[32];
  #pragma unroll
  for (int o = 0; o < 32; ++o) {
    const float* wr = &sW[o * 32];
    float acc = sB[o];
    #pragma unroll
    for (int c = 0; c < 32; ++c) acc = fmaf(xv[c], wr[c], acc);
    ao[(o & 1) * 16 + (o >> 1)] = acc;        // de-interleave heads
  }
  unsigned short* op = (p == 0 ? qo : p == 1 ? ko : vo) + (size_t)gid * 32;
  #pragma unroll
  for (int e = 0; e < 4; ++e) {
    uint4 pk4;
    pk4.x = (unsigned)f2bf(ao[e*8+0]) | ((unsigned)f2bf(ao[e*8+1]) << 16);
    pk4.y = (unsigned)f2bf(ao[e*8+2]) | ((unsigned)f2bf(ao[e*8+3]) << 16);
    pk4.z = (unsigned)f2bf(ao[e*8+4]) | ((unsigned)f2bf(ao[e*8+5]) << 16);
    pk4.w = (unsigned)f2bf(ao[e*8+6]) | ((unsigned)f2bf(ao[e*8+7]) << 16);
    *(uint4*)(op + e*8) = pk4;
  }
}

// ---- k2: tiled windowed attention (fused QK-exp-PV, tq-paired) + MFMA fusion GEMM ---
// Block = 4x8 = 32 locations, 256 threads (4 waves). 4 phases x 8 pair-slots.
#define TH 4
#define TW 8
#define NPOS 96   // 8x12 halo
#define KVSTR 40  // bf16 halo row stride in ushorts (80B, 16B-aligned)
#define OSTRU 264 // sO row stride (ushorts): 256 kk + 8 pad

__global__ __launch_bounds__(256, 3) void k_attn(
    const unsigned short* __restrict__ qi, const unsigned short* __restrict__ ki,
    const unsigned short* __restrict__ vi, const float* __restrict__ rel_table,
    const unsigned short* __restrict__ wctT, const float* __restrict__ bc,
    float* __restrict__ y2)
{
  __shared__ __align__(16) unsigned short sQ[NPOS*KVSTR]; // 7680 B
  __shared__ __align__(16) unsigned short sK[NPOS*KVSTR]; // 7680 B
  __shared__ __align__(16) unsigned short sV[NPOS*KVSTR]; // 7680 B
  __shared__ __align__(16) unsigned short sO[32*OSTRU];   // 16896 B
  __shared__ float sRT[162];
  __shared__ float sPar[NPOS];
  // total 40968 B -> 3 blocks/CU

  int tid = threadIdx.x;
  int lane = tid & 63, wv = tid >> 6;
  int b  = blockIdx.z;
  int h0 = blockIdx.y * TH, w0 = blockIdx.x * TW;

  for (int i = tid; i < 162; i += 256) sRT[i] = rel_table[i];
  if (tid < NPOS) {
    int ph = tid / 12, pw = tid - ph * 12;
    int h2 = h0 + ph - 2, w2 = w0 + pw - 2;
    bool valid = ((unsigned)h2 < HH) && ((unsigned)w2 < WW);
    sPar[tid] = (valid && (((h2 + w2) & 1) == 1)) ? 1.f : 0.f;
  }
  // halo staging: bf16 direct copy, zero for OOB. 3 arrays x 96 pos x 4 chunks = 1152
  for (int idx = tid; idx < 1152; idx += 256) {
    int arr = idx / 384;                  // 0=K, 1=V, 2=Q
    int rem = idx - arr * 384;
    int pos = rem >> 2, c8 = rem & 3;
    int ph = pos / 12, pw = pos - ph * 12;
    int h2 = h0 + ph - 2, w2 = w0 + pw - 2;
    uint4 val = make_uint4(0u, 0u, 0u, 0u);
    if (((unsigned)h2 < HH) && ((unsigned)w2 < WW)) {
      const unsigned short* src = (arr == 0 ? ki : arr == 1 ? vi : qi)
                       + ((size_t)((b << 14) + (h2 << 7) + w2)) * 32 + c8 * 8;
      val = *(const uint4*)src;
    }
    unsigned short* dp = (arr == 0 ? sK : arr == 1 ? sV : sQ) + pos * KVSTR + c8 * 8;
    *(uint4*)dp = val;
  }
  __syncthreads();

  f32x4 acc[2] = {{0.f,0.f,0.f,0.f},{0.f,0.f,0.f,0.f}};
  int ocol = wv * 16 + (lane & 15);

  for (int it = 0; it < 4; ++it) {
    int g = it * 8 + wv * 2 + (lane >> 5);    // half-wave-uniform pair-slot
    if (g < 26) {
      int nh = g & 1, pair = g >> 1;          // pair 0..12
      int tq0 = 2 * pair;
      bool two = (tq0 + 1) < 25;              // half-wave-uniform
      int tq1 = two ? tq0 + 1 : tq0;
      int loc = lane & 31;
      int ly = loc >> 3, lx = loc & 7;
      int posb = ly * 12 + lx;
      int iq0 = tq0 / 5, jq0 = tq0 - iq0 * 5;
      int iq1 = tq1 / 5, jq1 = tq1 - iq1 * 5;
      int pq0 = posb + iq0 * 12 + jq0;
      int pq1 = posb + iq1 * 12 + jq1;
      float parq0 = sPar[pq0], parq1 = sPar[pq1];
      float base0 = (parq0 == 1.f) ? 0.f : -100.f;
      float base1 = (parq1 == 1.f) ? 0.f : -100.f;
      float qf0[16], qf1[16];
      {
        const unsigned short* qp = &sQ[pq0*KVSTR + nh*16];
        uint4 qa = *(const uint4*)qp, qb = *(const uint4*)(qp + 8);
        unsigned uu[8] = {qa.x,qa.y,qa.z,qa.w,qb.x,qb.y,qb.z,qb.w};
        #pragma unroll
        for (int u = 0; u < 8; ++u) { qf0[2*u] = bflo(uu[u]); qf0[2*u+1] = bfhi(uu[u]); }
      }
      {
        const unsigned short* qp = &sQ[pq1*KVSTR + nh*16];
        uint4 qa = *(const uint4*)qp, qb = *(const uint4*)(qp + 8);
        unsigned uu[8] = {qa.x,qa.y,qa.z,qa.w,qb.x,qb.y,qb.z,qb.w};
        #pragma unroll
        for (int u = 0; u < 8; ++u) { qf1[2*u] = bflo(uu[u]); qf1[2*u+1] = bfhi(uu[u]); }
      }
      float sum0 = 0.f, sum1 = 0.f;
      float oo0[16], oo1[16];
      #pragma unroll
      for (int e = 0; e < 16; ++e) { oo0[e] = 0.f; oo1[e] = 0.f; }
      #pragma unroll 1
      for (int ik = 0; ik < 5; ++ik) {
        int pkb = posb + ik * 12;
        int rb0 = (((iq0 - ik + 4) * 9) + jq0 + 4) * 2 + nh;
        int rb1 = (((iq1 - ik + 4) * 9) + jq1 + 4) * 2 + nh;
        #pragma unroll 1
        for (int jk = 0; jk < 5; ++jk) {
          int pk = pkb + jk;
          const unsigned short* kp = &sK[pk*KVSTR + nh*16];
          uint4 ka = *(const uint4*)kp, kb = *(const uint4*)(kp + 8);
          float a0 = 0.f, a1 = 0.f;
          {
            unsigned uu[8] = {ka.x,ka.y,ka.z,ka.w,kb.x,kb.y,kb.z,kb.w};
            #pragma unroll
            for (int u = 0; u < 8; ++u) {
              float lo = bflo(uu[u]), hi = bfhi(uu[u]);
              a0 = fmaf(qf0[2*u], lo, a0); a0 = fmaf(qf0[2*u+1], hi, a0);
              a1 = fmaf(qf1[2*u], lo, a1); a1 = fmaf(qf1[2*u+1], hi, a1);
            }
          }
          float park = sPar[pk];
          float bias0 = sRT[rb0 - 2*jk];
          float bias1 = sRT[rb1 - 2*jk];
          float s0 = fmaf(a0, 0.25f, bias0) + ((parq0*park == 1.f) ? 0.f : -100.f) - base0;
          float s1 = fmaf(a1, 0.25f, bias1) + ((parq1*park == 1.f) ? 0.f : -100.f) - base1;
          float e0 = __expf(s0), e1 = __expf(s1);
          sum0 += e0; sum1 += e1;
          const unsigned short* vp = &sV[pk*KVSTR + nh*16];
          uint4 va = *(const uint4*)vp, vb = *(const uint4*)(vp + 8);
          {
            unsigned uu[8] = {va.x,va.y,va.z,va.w,vb.x,vb.y,vb.z,vb.w};
            #pragma unroll
            for (int u = 0; u < 8; ++u) {
              float lo = bflo(uu[u]), hi = bfhi(uu[u]);
              oo0[2*u]   = fmaf(e0, lo, oo0[2*u]);
              oo0[2*u+1] = fmaf(e0, hi, oo0[2*u+1]);
              oo1[2*u]   = fmaf(e1, lo, oo1[2*u]);
              oo1[2*u+1] = fmaf(e1, hi, oo1[2*u+1]);
            }
          }
        }
      }
      float inv0 = 1.f / sum0, inv1 = 1.f / sum1;
      int kl0 = (tq0 - it*8) * 32 + nh * 16;
      uint4 w4;
      w4.x = (unsigned)f2bf(oo0[0]*inv0)  | ((unsigned)f2bf(oo0[1]*inv0)  << 16);
      w4.y = (unsigned)f2bf(oo0[2]*inv0)  | ((unsigned)f2bf(oo0[3]*inv0)  << 16);
      w4.z = (unsigned)f2bf(oo0[4]*inv0)  | ((unsigned)f2bf(oo0[5]*inv0)  << 16);
      w4.w = (unsigned)f2bf(oo0[6]*inv0)  | ((unsigned)f2bf(oo0[7]*inv0)  << 16);
      *(uint4*)&sO[loc*OSTRU + kl0] = w4;
      w4.x = (unsigned)f2bf(oo0[8]*inv0)  | ((unsigned)f2bf(oo0[9]*inv0)  << 16);
      w4.y = (unsigned)f2bf(oo0[10]*inv0) | ((unsigned)f2bf(oo0[11]*inv0) << 16);
      w4.z = (unsigned)f2bf(oo0[12]*inv0) | ((unsigned)f2bf(oo0[13]*inv0) << 16);
      w4.w = (unsigned)f2bf(oo0[14]*inv0) | ((unsigned)f2bf(oo0[15]*inv0) << 16);
      *(uint4*)&sO[loc*OSTRU + kl0 + 8] = w4;
      if (two) {
        int kl1 = kl0 + 32;
        w4.x = (unsigned)f2bf(oo1[0]*inv1)  | ((unsigned)f2bf(oo1[1]*inv1)  << 16);
        w4.y = (unsigned)f2bf(oo1[2]*inv1)  | ((unsigned)f2bf(oo1[3]*inv1)  << 16);
        w4.z = (unsigned)f2bf(oo1[4]*inv1)  | ((unsigned)f2bf(oo1[5]*inv1)  << 16);
        w4.w = (unsigned)f2bf(oo1[6]*inv1)  | ((unsigned)f2bf(oo1[7]*inv1)  << 16);
        *(uint4*)&sO[loc*OSTRU + kl1] = w4;
        w4.x = (unsigned)f2bf(oo1[8]*inv1)  | ((unsigned)f2bf(oo1[9]*inv1)  << 16);
        w4.y = (unsigned)f2bf(oo1[10]*inv1) | ((unsigned)f2bf(oo1[11]*inv1) << 16);
        w4.z = (unsigned)f2bf(oo1[12]*inv1) | ((unsigned)f2bf(oo1[13]*inv1) << 16);
        w4.w = (unsigned)f2bf(oo1[14]*inv1) | ((unsigned)f2bf(oo1[15]*inv1) << 16);
        *(uint4*)&sO[loc*OSTRU + kl1 + 8] = w4;
      }
    }
    __syncthreads();
    // MFMA phase: K-chunk [it*256, it*256 + nk*32)
    int nk = (it < 3) ? 8 : 1;
    const unsigned short* bcol = wctT + (size_t)ocol * 800 + it * 256 + (lane >> 4) * 8;
    for (int kt = 0; kt < nk; ++kt) {
      bf16x8 bfrag = *(const bf16x8*)(bcol + kt * 32);
      #pragma unroll
      for (int mt = 0; mt < 2; ++mt) {
        bf16x8 afrag = *(const bf16x8*)&sO[(mt*16 + (lane & 15))*OSTRU + kt*32 + (lane >> 4)*8];
        acc[mt] = __builtin_amdgcn_mfma_f32_16x16x32_bf16(afrag, bfrag, acc[mt], 0, 0, 0);
      }
    }
    __syncthreads();
  }
  // epilogue: y2[loc][o] = acc + bc[o]
  float bco = bc[ocol];
  #pragma unroll
  for (int mt = 0; mt < 2; ++mt) {
    #pragma unroll
    for (int r2 = 0; r2 < 4; ++r2) {
      int loc = mt * 16 + (lane >> 4) * 4 + r2;
      int ly = loc >> 3, lx = loc & 7;
      int gid = (b << 14) + ((h0 + ly) << 7) + (w0 + lx);
      y2[(size_t)gid * 64 + ocol] = acc[mt][r2] + bco;
    }
  }
}

// ---- k3: LN + MLP via MFMA (GELU exact) + residual + transpose store ----------------
__global__ __launch_bounds__(256) void k_mlp(
    const float* __restrict__ y2, const float* __restrict__ n2w,
    const float* __restrict__ n2b, const unsigned short* __restrict__ w1b,
    const float* __restrict__ b1, const unsigned short* __restrict__ w2b,
    const float* __restrict__ b2, float* __restrict__ out)
{
  __shared__ __align__(16) unsigned short sA[64*72];   // 9216 B  (LN'd input, bf16)
  __shared__ __align__(16) unsigned short sH[64*136];  // 17408 B (GELU output, bf16)
  int tid = threadIdx.x;
  int lane = tid & 63, wv = tid >> 6;
  int m0 = blockIdx.x * 64;
  // ---- LN: 4 threads per row
  {
    int r = tid >> 2, qd = tid & 3;
    const float* yp = y2 + (size_t)(m0 + r) * 64 + qd * 16;
    float xv[16];
    float s = 0.f;
    #pragma unroll
    for (int e = 0; e < 4; ++e) {
      float4 t4 = *(const float4*)(yp + e*4);
      xv[4*e] = t4.x; xv[4*e+1] = t4.y; xv[4*e+2] = t4.z; xv[4*e+3] = t4.w;
      s += t4.x + t4.y + t4.z + t4.w;
    }
    s += __shfl_xor(s, 1);
    s += __shfl_xor(s, 2);
    float mean = s * (1.f/64.f);
    float v = 0.f;
    #pragma unroll
    for (int e = 0; e < 16; ++e) { float d = xv[e] - mean; v = fmaf(d, d, v); }
    v += __shfl_xor(v, 1);
    v += __shfl_xor(v, 2);
    float rs = rsqrtf(v * (1.f/64.f) + 1e-5f);
    #pragma unroll
    for (int u = 0; u < 8; ++u) {
      int c0 = qd*16 + 2*u;
      float h0v = (xv[2*u]   - mean) * rs * n2w[c0]   + n2b[c0];
      float h1v = (xv[2*u+1] - mean) * rs * n2w[c0+1] + n2b[c0+1];
      *(unsigned*)&sA[r*72 + c0] = (unsigned)f2bf(h0v) | ((unsigned)f2bf(h1v) << 16);
    }
  }
  __syncthreads();
  // ---- GEMM1: [64x64] x W1^T -> [64x128], n-slice 32 per wave
  f32x4 acc1[4][2];
  #pragma unroll
  for (int mt = 0; mt < 4; ++mt)
    #pragma unroll
    for (int nt = 0; nt < 2; ++nt) acc1[mt][nt] = (f32x4){0.f,0.f,0.f,0.f};
  #pragma unroll
  for (int kt = 0; kt < 2; ++kt) {
    #pragma unroll
    for (int nt = 0; nt < 2; ++nt) {
      int ncol = wv*32 + nt*16 + (lane & 15);
      bf16x8 bfrag = *(const bf16x8*)(w1b + ncol*64 + kt*32 + (lane >> 4)*8);
      #pragma unroll
      for (int mt = 0; mt < 4; ++mt) {
        bf16x8 afrag = *(const bf16x8*)&sA[(mt*16 + (lane & 15))*72 + kt*32 + (lane >> 4)*8];
        acc1[mt][nt] = __builtin_amdgcn_mfma_f32_16x16x32_bf16(afrag, bfrag, acc1[mt][nt], 0, 0, 0);
      }
    }
  }
  // ---- bias + exact GELU -> sH (bf16)
  #pragma unroll
  for (int nt = 0; nt < 2; ++nt) {
    int ncol = wv*32 + nt*16 + (lane & 15);
    float b1v = b1[ncol];
    #pragma unroll
    for (int mt = 0; mt < 4; ++mt) {
      #pragma unroll
      for (int r2 = 0; r2 < 4; ++r2) {
        int mrow = mt*16 + (lane >> 4)*4 + r2;
        float h = acc1[mt][nt][r2] + b1v;
        float g = 0.5f * h * (1.f + erff(h * 0.70710678118f));
        sH[mrow*136 + ncol] = f2bf(g);
      }
    }
  }
  __syncthreads();
  // ---- GEMM2: [64x128] x W2^T -> [64x64], n-slice 16 per wave
  f32x4 acc2[4];
  #pragma unroll
  for (int mt = 0; mt < 4; ++mt) acc2[mt] = (f32x4){0.f,0.f,0.f,0.f};
  int ocol = wv*16 + (lane & 15);
  #pragma unroll
  for (int kt = 0; kt < 4; ++kt) {
    bf16x8 bfrag = *(const bf16x8*)(w2b + ocol*128 + kt*32 + (lane >> 4)*8);
    #pragma unroll
    for (int mt = 0; mt < 4; ++mt) {
      bf16x8 afrag = *(const bf16x8*)&sH[(mt*16 + (lane & 15))*136 + kt*32 + (lane >> 4)*8];
      acc2[mt] = __builtin_amdgcn_mfma_f32_16x16x32_bf16(afrag, bfrag, acc2[mt], 0, 0, 0);
    }
  }
  // ---- residual + bias + transpose store
  float b2v = b2[ocol];
  int bb = m0 >> 14;
  #pragma unroll
  for (int mt = 0; mt < 4; ++mt) {
    int mrow = mt*16 + (lane >> 4)*4;
    int l = m0 + mrow;
    const float* yp = y2 + (size_t)l * 64 + ocol;
    float4 o4;
    o4.x = yp[0]   + acc2[mt][0] + b2v;
    o4.y = yp[64]  + acc2[mt][1] + b2v;
    o4.z = yp[128] + acc2[mt][2] + b2v;
    o4.w = yp[192] + acc2[mt][3] + b2v;
    *(float4*)&out[(size_t)bb * 64 * LL + (size_t)ocol * LL + (l - (bb << 14))] = o4;
  }
}

extern "C" void kernel_launch(void* const* d_in, const int* in_sizes, int n_in,
                              void* d_out, int out_size, void* d_ws, size_t ws_size,
                              hipStream_t stream) {
  const float* x         = (const float*)d_in[0];
  const float* qkv_w     = (const float*)d_in[1];
  const float* qkv_b     = (const float*)d_in[2];
  const float* rel_table = (const float*)d_in[3];
  const float* n1w       = (const float*)d_in[4];
  const float* n1b       = (const float*)d_in[5];
  const float* n2w       = (const float*)d_in[6];
  const float* n2b       = (const float*)d_in[7];
  const float* proj_w    = (const float*)d_in[8];
  const float* proj_b    = (const float*)d_in[9];
  const float* fw        = (const float*)d_in[10];
  const float* fb        = (const float*)d_in[11];
  const float* w1        = (const float*)d_in[12];
  const float* b1        = (const float*)d_in[13];
  const float* w2        = (const float*)d_in[14];
  const float* b2        = (const float*)d_in[15];

  char* ws = (char*)d_ws;
  unsigned short* q    = (unsigned short*)(ws);                    // BL*32 bf16 = 2MB
  unsigned short* k    = (unsigned short*)(ws + 2097152);          // 2MB
  unsigned short* v    = (unsigned short*)(ws + 4194304);          // 2MB
  float*          y2   = (float*)(ws + 6291456);                   // BL*64 f32 = 8MB
  unsigned short* wctT = (unsigned short*)(ws + 14680064);         // 64*800 bf16
  float*          bc   = (float*)(ws + 14782464);                  // 64 f32
  unsigned short* w1b  = (unsigned short*)(ws + 14782720);         // 8192 bf16
  unsigned short* w2b  = (unsigned short*)(ws + 14799104);         // 8192 bf16
  float* out = (float*)d_out;

  k_combine<<<203, 256, 0, stream>>>(proj_w, proj_b, fw, fb, w1, w2, wctT, bc, w1b, w2b);
  k_ln_qkv<<<dim3(BL/128, 3), 128, 0, stream>>>(x, qkv_w, qkv_b, n1w, n1b, q, k, v);
  k_attn<<<dim3(WW/TW, HH/TH, 2), 256, 0, stream>>>(q, k, v, rel_table, wctT, bc, y2);
  k_mlp<<<BL/64, 256, 0, stream>>>(y2, n2w, n2b, w1b, b1, w2b, b2, out);
}

// Round 8
// 103.410 us; speedup vs baseline: 17.4675x; 1.1164x over previous
//
#include <hip/hip_runtime.h>
#include <cstdint>
#include <cstddef>

#define HH 128
#define WW 128
#define LL 16384   // HH*WW
#define BL 32768   // B*LL

typedef float  f32x4  __attribute__((ext_vector_type(4)));
typedef short  bf16x8 __attribute__((ext_vector_type(8)));
typedef __fp16 h2     __attribute__((ext_vector_type(2)));

union U32H { unsigned u; h2 h; };

static __device__ __forceinline__ float fdot2(h2 a, h2 b, float c) {
  return __builtin_amdgcn_fdot2(a, b, c, false);
}
static __device__ __forceinline__ unsigned pkh2(float a, float b) {
  h2 h = __builtin_amdgcn_cvt_pkrtz(a, b);
  U32H t; t.h = h; return t.u;
}
static __device__ __forceinline__ unsigned short f2bf(float x) {
  union { float f; unsigned int u; } c; c.f = x;
  unsigned int r = (c.u + 0x7fffu + ((c.u >> 16) & 1u)) >> 16;   // RNE
  return (unsigned short)r;
}

#define LOADH8(dst, ptr) { \
  uint4 _a = *(const uint4*)(ptr); uint4 _b = *(const uint4*)((ptr)+8); U32H _t; \
  _t.u=_a.x; dst[0]=_t.h; _t.u=_a.y; dst[1]=_t.h; _t.u=_a.z; dst[2]=_t.h; _t.u=_a.w; dst[3]=_t.h; \
  _t.u=_b.x; dst[4]=_t.h; _t.u=_b.y; dst[5]=_t.h; _t.u=_b.z; dst[6]=_t.h; _t.u=_b.w; dst[7]=_t.h; }

// ---- k0: fold proj into fusion weight (bf16 B^T [64][800], kk = t*32+c); cast w1/w2 --
__global__ __launch_bounds__(256) void k_combine(
    const float* __restrict__ proj_w, const float* __restrict__ proj_b,
    const float* __restrict__ fw, const float* __restrict__ fb,
    const float* __restrict__ w1, const float* __restrict__ w2,
    unsigned short* __restrict__ wctT, float* __restrict__ bc,
    unsigned short* __restrict__ w1b, unsigned short* __restrict__ w2b)
{
  if (blockIdx.x == 200) {
    int o = threadIdx.x;
    if (o < 64) {
      float acc = proj_b[o];
      for (int m = 0; m < 64; ++m) acc = fmaf(proj_w[o*64+m], fb[m], acc);
      bc[o] = acc;
    }
    return;
  }
  if (blockIdx.x == 201) {
    for (int i = threadIdx.x; i < 8192; i += 256) w1b[i] = f2bf(w1[i]);
    return;
  }
  if (blockIdx.x == 202) {
    for (int i = threadIdx.x; i < 8192; i += 256) w2b[i] = f2bf(w2[i]);
    return;
  }
  int gid = blockIdx.x * 256 + threadIdx.x;   // 0..51199 = o*800 + kk
  int o  = gid / 800;
  int kk = gid - o * 800;
  int c  = kk & 31;        // de-interleaved channel (nh*16+d)
  int t  = kk >> 5;        // window position 0..24
  int in = c * 25 + t;     // fusion weight flat index
  float acc = 0.f;
  for (int m = 0; m < 64; ++m) acc = fmaf(proj_w[o*64+m], fw[m*800+in], acc);
  wctT[gid] = f2bf(acc);
}

// ---- k1: LayerNorm + QKV, fp16 out, de-interleaved (c' = nh*16 + d); 3-way split ----
__global__ __launch_bounds__(128) void k_ln_qkv(
    const float* __restrict__ x, const float* __restrict__ qkv_w,
    const float* __restrict__ qkv_b, const float* __restrict__ n1w,
    const float* __restrict__ n1b, unsigned short* __restrict__ qo,
    unsigned short* __restrict__ ko, unsigned short* __restrict__ vo)
{
  __shared__ float sW[32*32];
  __shared__ float sB[32];
  __shared__ float sNw[32], sNb[32];
  int p = blockIdx.y;                         // 0=q 1=k 2=v
  for (int i = threadIdx.x; i < 32*32; i += 128) sW[i] = qkv_w[p*1024 + i];
  if (threadIdx.x < 32) {
    sB[threadIdx.x]  = qkv_b[p*32 + threadIdx.x];
    sNw[threadIdx.x] = n1w[threadIdx.x];
    sNb[threadIdx.x] = n1b[threadIdx.x];
  }
  __syncthreads();
  int gid = blockIdx.x * 128 + threadIdx.x;   // 0..BL-1
  int b = gid >> 14, l = gid & (LL - 1);
  const float* xp = x + (size_t)b * 32 * LL + l;
  float xv[32];
  float mean = 0.f;
  #pragma unroll
  for (int c = 0; c < 32; ++c) { xv[c] = xp[(size_t)c * LL]; mean += xv[c]; }
  mean *= 0.03125f;
  float var = 0.f;
  #pragma unroll
  for (int c = 0; c < 32; ++c) { float d = xv[c] - mean; var = fmaf(d, d, var); }
  float rs = rsqrtf(var * 0.03125f + 1e-5f);
  #pragma unroll
  for (int c = 0; c < 32; ++c) xv[c] = (xv[c] - mean) * rs * sNw[c] + sNb[c];
  float ao[32];
  #pragma unroll
  for (int o = 0; o < 32; ++o) {
    const float* wr = &sW[o * 32];
    float acc = sB[o];
    #pragma unroll
    for (int c = 0; c < 32; ++c) acc = fmaf(xv[c], wr[c], acc);
    ao[(o & 1) * 16 + (o >> 1)] = acc;        // de-interleave heads
  }
  unsigned short* op = (p == 0 ? qo : p == 1 ? ko : vo) + (size_t)gid * 32;
  #pragma unroll
  for (int e = 0; e < 4; ++e) {
    uint4 pk4;
    pk4.x = pkh2(ao[e*8+0], ao[e*8+1]);
    pk4.y = pkh2(ao[e*8+2], ao[e*8+3]);
    pk4.z = pkh2(ao[e*8+4], ao[e*8+5]);
    pk4.w = pkh2(ao[e*8+6], ao[e*8+7]);
    *(uint4*)(op + e*8) = pk4;
  }
}

// ---- k2: tiled windowed attention (fused QK-exp-PV, tq-QUAD tasks) + MFMA GEMM ------
// Block = 4x8 = 32 locations, 256 threads (4 waves). 2 compute + 2 MFMA phases.
#define TH 4
#define TW 8
#define NPOS 96   // 8x12 halo
#define KVSTR 40  // fp16 halo row stride in ushorts (80B, 16B-aligned)
#define OSTRU 520 // sO row stride (ushorts): 512 kk + 8 pad

__global__ __launch_bounds__(256, 2) void k_attn(
    const unsigned short* __restrict__ qi, const unsigned short* __restrict__ ki,
    const unsigned short* __restrict__ vi, const float* __restrict__ rel_table,
    const unsigned short* __restrict__ wctT, const float* __restrict__ bc,
    float* __restrict__ y2)
{
  __shared__ __align__(16) unsigned short sQ[NPOS*KVSTR]; // 7680 B
  __shared__ __align__(16) unsigned short sK[NPOS*KVSTR]; // 7680 B
  __shared__ __align__(16) unsigned short sV[NPOS*KVSTR]; // 7680 B
  __shared__ __align__(16) unsigned short sO[32*OSTRU];   // 33280 B
  __shared__ float sRT[162];
  __shared__ float sPar[NPOS];
  // total ~57.3 KB -> 2 blocks/CU

  int tid = threadIdx.x;
  int lane = tid & 63, wv = tid >> 6;
  int b  = blockIdx.z;
  int h0 = blockIdx.y * TH, w0 = blockIdx.x * TW;

  for (int i = tid; i < 162; i += 256) sRT[i] = rel_table[i];
  if (tid < NPOS) {
    int ph = tid / 12, pw = tid - ph * 12;
    int h2v = h0 + ph - 2, w2v = w0 + pw - 2;
    bool valid = ((unsigned)h2v < HH) && ((unsigned)w2v < WW);
    sPar[tid] = (valid && (((h2v + w2v) & 1) == 1)) ? 1.f : 0.f;
  }
  // halo staging: fp16 bit-copy, zero for OOB. 3 arrays x 96 pos x 4 chunks = 1152
  for (int idx = tid; idx < 1152; idx += 256) {
    int arr = idx / 384;                  // 0=K, 1=V, 2=Q
    int rem = idx - arr * 384;
    int pos = rem >> 2, c8 = rem & 3;
    int ph = pos / 12, pw = pos - ph * 12;
    int h2v = h0 + ph - 2, w2v = w0 + pw - 2;
    uint4 val = make_uint4(0u, 0u, 0u, 0u);
    if (((unsigned)h2v < HH) && ((unsigned)w2v < WW)) {
      const unsigned short* src = (arr == 0 ? ki : arr == 1 ? vi : qi)
                       + ((size_t)((b << 14) + (h2v << 7) + w2v)) * 32 + c8 * 8;
      val = *(const uint4*)src;
    }
    unsigned short* dp = (arr == 0 ? sK : arr == 1 ? sV : sQ) + pos * KVSTR + c8 * 8;
    *(uint4*)dp = val;
  }
  __syncthreads();

  f32x4 acc[2] = {{0.f,0.f,0.f,0.f},{0.f,0.f,0.f,0.f}};
  int ocol = wv * 16 + (lane & 15);

  for (int it = 0; it < 2; ++it) {
    int g = wv * 2 + (lane >> 5);             // 0..7, half-wave uniform
    int qd = it * 4 + (g >> 1);               // quad index 0..7
    int nh = g & 1;
    int nh16 = nh * 16;
    if (qd < 7) {
      int nrr = (qd < 6) ? 4 : 1;             // valid rows in quad (tq<=24)
      int loc = lane & 31;
      int ly = loc >> 3, lx = loc & 7;
      int posb = ly * 12 + lx;
      int tqb = 4 * qd;
      // per-row setup
      int tq0 = tqb, tq1 = tqb+1, tq2 = tqb+2, tq3 = tqb+3;
      int iq0 = tq0/5, jq0 = tq0 - iq0*5;
      int iq1 = tq1/5, jq1 = tq1 - iq1*5;
      int iq2 = tq2/5, jq2 = tq2 - iq2*5;
      int iq3 = tq3/5, jq3 = tq3 - iq3*5;
      int pq0 = posb + iq0*12 + jq0; pq0 = pq0 > 95 ? 95 : pq0;
      int pq1 = posb + iq1*12 + jq1; pq1 = pq1 > 95 ? 95 : pq1;
      int pq2 = posb + iq2*12 + jq2; pq2 = pq2 > 95 ? 95 : pq2;
      int pq3 = posb + iq3*12 + jq3; pq3 = pq3 > 95 ? 95 : pq3;
      float parq0 = sPar[pq0], parq1 = sPar[pq1], parq2 = sPar[pq2], parq3 = sPar[pq3];
      h2 q0[8], q1[8], q2[8], q3[8];
      LOADH8(q0, &sQ[pq0*KVSTR + nh16]);
      LOADH8(q1, &sQ[pq1*KVSTR + nh16]);
      LOADH8(q2, &sQ[pq2*KVSTR + nh16]);
      LOADH8(q3, &sQ[pq3*KVSTR + nh16]);
      float s0 = 0.f, s1 = 0.f, s2 = 0.f, s3 = 0.f;
      float oo0[16], oo1[16], oo2[16], oo3[16];
      #pragma unroll
      for (int e = 0; e < 16; ++e) { oo0[e]=0.f; oo1[e]=0.f; oo2[e]=0.f; oo3[e]=0.f; }
      #pragma unroll 1
      for (int ik = 0; ik < 5; ++ik) {
        int rb0 = ((iq0-ik+4)*9 + jq0 + 4)*2 + nh;
        int rb1 = ((iq1-ik+4)*9 + jq1 + 4)*2 + nh;
        int rb2 = ((iq2-ik+4)*9 + jq2 + 4)*2 + nh;
        int rb3 = ((iq3-ik+4)*9 + jq3 + 4)*2 + nh;
        #pragma unroll
        for (int jk = 0; jk < 5; ++jk) {
          int pk = posb + ik*12 + jk;
          h2 kh[8];
          LOADH8(kh, &sK[pk*KVSTR + nh16]);
          float park = sPar[pk];
          float mk = (park == 1.f) ? 0.f : -100.f;
          float a0 = 0.f, a1 = 0.f, a2 = 0.f, a3 = 0.f;
          #pragma unroll
          for (int u = 0; u < 8; ++u) {
            a0 = fdot2(q0[u], kh[u], a0);
            a1 = fdot2(q1[u], kh[u], a1);
            a2 = fdot2(q2[u], kh[u], a2);
            a3 = fdot2(q3[u], kh[u], a3);
          }
          int i0 = rb0 - 2*jk; i0 = i0 > 161 ? 161 : i0;
          int i1 = rb1 - 2*jk; i1 = i1 > 161 ? 161 : i1;
          int i2 = rb2 - 2*jk; i2 = i2 > 161 ? 161 : i2;
          int i3 = rb3 - 2*jk; i3 = i3 > 161 ? 161 : i3;
          float e0 = __expf(fmaf(parq0, mk, fmaf(a0, 0.25f, sRT[i0])));
          float e1 = __expf(fmaf(parq1, mk, fmaf(a1, 0.25f, sRT[i1])));
          float e2 = __expf(fmaf(parq2, mk, fmaf(a2, 0.25f, sRT[i2])));
          float e3 = __expf(fmaf(parq3, mk, fmaf(a3, 0.25f, sRT[i3])));
          s0 += e0; s1 += e1; s2 += e2; s3 += e3;
          h2 vh[8];
          LOADH8(vh, &sV[pk*KVSTR + nh16]);
          #pragma unroll
          for (int u = 0; u < 8; ++u) {
            float lo = (float)vh[u].x, hi = (float)vh[u].y;
            oo0[2*u] = fmaf(e0, lo, oo0[2*u]); oo0[2*u+1] = fmaf(e0, hi, oo0[2*u+1]);
            oo1[2*u] = fmaf(e1, lo, oo1[2*u]); oo1[2*u+1] = fmaf(e1, hi, oo1[2*u+1]);
            oo2[2*u] = fmaf(e2, lo, oo2[2*u]); oo2[2*u+1] = fmaf(e2, hi, oo2[2*u+1]);
            oo3[2*u] = fmaf(e3, lo, oo3[2*u]); oo3[2*u+1] = fmaf(e3, hi, oo3[2*u+1]);
          }
        }
      }
      // write valid rows to sO (bf16), kl = (tq - it*16)*32 + nh*16
      #define WRITE_ROW(OO, SS, TQ) { \
        float inv = 1.f / (SS); \
        int kl = ((TQ) - it*16) * 32 + nh16; \
        uint4 w4; \
        w4.x = (unsigned)f2bf(OO[0]*inv)  | ((unsigned)f2bf(OO[1]*inv)  << 16); \
        w4.y = (unsigned)f2bf(OO[2]*inv)  | ((unsigned)f2bf(OO[3]*inv)  << 16); \
        w4.z = (unsigned)f2bf(OO[4]*inv)  | ((unsigned)f2bf(OO[5]*inv)  << 16); \
        w4.w = (unsigned)f2bf(OO[6]*inv)  | ((unsigned)f2bf(OO[7]*inv)  << 16); \
        *(uint4*)&sO[loc*OSTRU + kl] = w4; \
        w4.x = (unsigned)f2bf(OO[8]*inv)  | ((unsigned)f2bf(OO[9]*inv)  << 16); \
        w4.y = (unsigned)f2bf(OO[10]*inv) | ((unsigned)f2bf(OO[11]*inv) << 16); \
        w4.z = (unsigned)f2bf(OO[12]*inv) | ((unsigned)f2bf(OO[13]*inv) << 16); \
        w4.w = (unsigned)f2bf(OO[14]*inv) | ((unsigned)f2bf(OO[15]*inv) << 16); \
        *(uint4*)&sO[loc*OSTRU + kl + 8] = w4; }
      WRITE_ROW(oo0, s0, tq0);
      if (1 < nrr) WRITE_ROW(oo1, s1, tq1);
      if (2 < nrr) WRITE_ROW(oo2, s2, tq2);
      if (3 < nrr) WRITE_ROW(oo3, s3, tq3);
      #undef WRITE_ROW
    }
    __syncthreads();
    // MFMA phase: kt in [it*16, it*16+ktn)
    int ktn = it ? 9 : 16;
    const unsigned short* bcol = wctT + (size_t)ocol * 800 + it * 512 + (lane >> 4) * 8;
    for (int kt = 0; kt < ktn; ++kt) {
      bf16x8 bfrag = *(const bf16x8*)(bcol + kt * 32);
      #pragma unroll
      for (int mt = 0; mt < 2; ++mt) {
        bf16x8 afrag = *(const bf16x8*)&sO[(mt*16 + (lane & 15))*OSTRU + kt*32 + (lane >> 4)*8];
        acc[mt] = __builtin_amdgcn_mfma_f32_16x16x32_bf16(afrag, bfrag, acc[mt], 0, 0, 0);
      }
    }
    __syncthreads();
  }
  // epilogue: y2[loc][o] = acc + bc[o]
  float bco = bc[ocol];
  #pragma unroll
  for (int mt = 0; mt < 2; ++mt) {
    #pragma unroll
    for (int r2 = 0; r2 < 4; ++r2) {
      int loc = mt * 16 + (lane >> 4) * 4 + r2;
      int ly = loc >> 3, lx = loc & 7;
      int gid = (b << 14) + ((h0 + ly) << 7) + (w0 + lx);
      y2[(size_t)gid * 64 + ocol] = acc[mt][r2] + bco;
    }
  }
}

// ---- k3: LN + MLP via MFMA (GELU exact) + residual + transpose store ----------------
__global__ __launch_bounds__(256) void k_mlp(
    const float* __restrict__ y2, const float* __restrict__ n2w,
    const float* __restrict__ n2b, const unsigned short* __restrict__ w1b,
    const float* __restrict__ b1, const unsigned short* __restrict__ w2b,
    const float* __restrict__ b2, float* __restrict__ out)
{
  __shared__ __align__(16) unsigned short sA[64*72];   // 9216 B  (LN'd input, bf16)
  __shared__ __align__(16) unsigned short sH[64*136];  // 17408 B (GELU output, bf16)
  int tid = threadIdx.x;
  int lane = tid & 63, wv = tid >> 6;
  int m0 = blockIdx.x * 64;
  // ---- LN: 4 threads per row
  {
    int r = tid >> 2, qd = tid & 3;
    const float* yp = y2 + (size_t)(m0 + r) * 64 + qd * 16;
    float xv[16];
    float s = 0.f;
    #pragma unroll
    for (int e = 0; e < 4; ++e) {
      float4 t4 = *(const float4*)(yp + e*4);
      xv[4*e] = t4.x; xv[4*e+1] = t4.y; xv[4*e+2] = t4.z; xv[4*e+3] = t4.w;
      s += t4.x + t4.y + t4.z + t4.w;
    }
    s += __shfl_xor(s, 1);
    s += __shfl_xor(s, 2);
    float mean = s * (1.f/64.f);
    float v = 0.f;
    #pragma unroll
    for (int e = 0; e < 16; ++e) { float d = xv[e] - mean; v = fmaf(d, d, v); }
    v += __shfl_xor(v, 1);
    v += __shfl_xor(v, 2);
    float rs = rsqrtf(v * (1.f/64.f) + 1e-5f);
    #pragma unroll
    for (int u = 0; u < 8; ++u) {
      int c0 = qd*16 + 2*u;
      float h0v = (xv[2*u]   - mean) * rs * n2w[c0]   + n2b[c0];
      float h1v = (xv[2*u+1] - mean) * rs * n2w[c0+1] + n2b[c0+1];
      *(unsigned*)&sA[r*72 + c0] = (unsigned)f2bf(h0v) | ((unsigned)f2bf(h1v) << 16);
    }
  }
  __syncthreads();
  // ---- GEMM1: [64x64] x W1^T -> [64x128], n-slice 32 per wave
  f32x4 acc1[4][2];
  #pragma unroll
  for (int mt = 0; mt < 4; ++mt)
    #pragma unroll
    for (int nt = 0; nt < 2; ++nt) acc1[mt][nt] = (f32x4){0.f,0.f,0.f,0.f};
  #pragma unroll
  for (int kt = 0; kt < 2; ++kt) {
    #pragma unroll
    for (int nt = 0; nt < 2; ++nt) {
      int ncol = wv*32 + nt*16 + (lane & 15);
      bf16x8 bfrag = *(const bf16x8*)(w1b + ncol*64 + kt*32 + (lane >> 4)*8);
      #pragma unroll
      for (int mt = 0; mt < 4; ++mt) {
        bf16x8 afrag = *(const bf16x8*)&sA[(mt*16 + (lane & 15))*72 + kt*32 + (lane >> 4)*8];
        acc1[mt][nt] = __builtin_amdgcn_mfma_f32_16x16x32_bf16(afrag, bfrag, acc1[mt][nt], 0, 0, 0);
      }
    }
  }
  // ---- bias + exact GELU -> sH (bf16)
  #pragma unroll
  for (int nt = 0; nt < 2; ++nt) {
    int ncol = wv*32 + nt*16 + (lane & 15);
    float b1v = b1[ncol];
    #pragma unroll
    for (int mt = 0; mt < 4; ++mt) {
      #pragma unroll
      for (int r2 = 0; r2 < 4; ++r2) {
        int mrow = mt*16 + (lane >> 4)*4 + r2;
        float h = acc1[mt][nt][r2] + b1v;
        float g = 0.5f * h * (1.f + erff(h * 0.70710678118f));
        sH[mrow*136 + ncol] = f2bf(g);
      }
    }
  }
  __syncthreads();
  // ---- GEMM2: [64x128] x W2^T -> [64x64], n-slice 16 per wave
  f32x4 acc2[4];
  #pragma unroll
  for (int mt = 0; mt < 4; ++mt) acc2[mt] = (f32x4){0.f,0.f,0.f,0.f};
  int ocol = wv*16 + (lane & 15);
  #pragma unroll
  for (int kt = 0; kt < 4; ++kt) {
    bf16x8 bfrag = *(const bf16x8*)(w2b + ocol*128 + kt*32 + (lane >> 4)*8);
    #pragma unroll
    for (int mt = 0; mt < 4; ++mt) {
      bf16x8 afrag = *(const bf16x8*)&sH[(mt*16 + (lane & 15))*136 + kt*32 + (lane >> 4)*8];
      acc2[mt] = __builtin_amdgcn_mfma_f32_16x16x32_bf16(afrag, bfrag, acc2[mt], 0, 0, 0);
    }
  }
  // ---- residual + bias + transpose store
  float b2v = b2[ocol];
  int bb = m0 >> 14;
  #pragma unroll
  for (int mt = 0; mt < 4; ++mt) {
    int mrow = mt*16 + (lane >> 4)*4;
    int l = m0 + mrow;
    const float* yp = y2 + (size_t)l * 64 + ocol;
    float4 o4;
    o4.x = yp[0]   + acc2[mt][0] + b2v;
    o4.y = yp[64]  + acc2[mt][1] + b2v;
    o4.z = yp[128] + acc2[mt][2] + b2v;
    o4.w = yp[192] + acc2[mt][3] + b2v;
    *(float4*)&out[(size_t)bb * 64 * LL + (size_t)ocol * LL + (l - (bb << 14))] = o4;
  }
}

extern "C" void kernel_launch(void* const* d_in, const int* in_sizes, int n_in,
                              void* d_out, int out_size, void* d_ws, size_t ws_size,
                              hipStream_t stream) {
  const float* x         = (const float*)d_in[0];
  const float* qkv_w     = (const float*)d_in[1];
  const float* qkv_b     = (const float*)d_in[2];
  const float* rel_table = (const float*)d_in[3];
  const float* n1w       = (const float*)d_in[4];
  const float* n1b       = (const float*)d_in[5];
  const float* n2w       = (const float*)d_in[6];
  const float* n2b       = (const float*)d_in[7];
  const float* proj_w    = (const float*)d_in[8];
  const float* proj_b    = (const float*)d_in[9];
  const float* fw        = (const float*)d_in[10];
  const float* fb        = (const float*)d_in[11];
  const float* w1        = (const float*)d_in[12];
  const float* b1        = (const float*)d_in[13];
  const float* w2        = (const float*)d_in[14];
  const float* b2        = (const float*)d_in[15];

  char* ws = (char*)d_ws;
  unsigned short* q    = (unsigned short*)(ws);                    // BL*32 fp16 = 2MB
  unsigned short* k    = (unsigned short*)(ws + 2097152);          // 2MB
  unsigned short* v    = (unsigned short*)(ws + 4194304);          // 2MB
  float*          y2   = (float*)(ws + 6291456);                   // BL*64 f32 = 8MB
  unsigned short* wctT = (unsigned short*)(ws + 14680064);         // 64*800 bf16
  float*          bc   = (float*)(ws + 14782464);                  // 64 f32
  unsigned short* w1b  = (unsigned short*)(ws + 14782720);         // 8192 bf16
  unsigned short* w2b  = (unsigned short*)(ws + 14799104);         // 8192 bf16
  float* out = (float*)d_out;

  k_combine<<<203, 256, 0, stream>>>(proj_w, proj_b, fw, fb, w1, w2, wctT, bc, w1b, w2b);
  k_ln_qkv<<<dim3(BL/128, 3), 128, 0, stream>>>(x, qkv_w, qkv_b, n1w, n1b, q, k, v);
  k_attn<<<dim3(WW/TW, HH/TH, 2), 256, 0, stream>>>(q, k, v, rel_table, wctT, bc, y2);
  k_mlp<<<BL/64, 256, 0, stream>>>(y2, n2w, n2b, w1b, b1, w2b, b2, out);
}

// Round 9
// 94.285 us; speedup vs baseline: 19.1580x; 1.0968x over previous
//
#include <hip/hip_runtime.h>
#include <cstdint>
#include <cstddef>

#define HH 128
#define WW 128
#define LL 16384   // HH*WW
#define BL 32768   // B*LL

typedef float  f32x4  __attribute__((ext_vector_type(4)));
typedef __fp16 h2     __attribute__((ext_vector_type(2)));
typedef __fp16 h8     __attribute__((ext_vector_type(8)));

union U32H { unsigned u; h2 h; };

static __device__ __forceinline__ float fdot2(h2 a, h2 b, float c) {
  return __builtin_amdgcn_fdot2(a, b, c, false);
}
static __device__ __forceinline__ unsigned pkh2(float a, float b) {
  h2 h = __builtin_amdgcn_cvt_pkrtz(a, b);
  U32H t; t.h = h; return t.u;
}
static __device__ __forceinline__ h2 bcasth(float a) {
  return __builtin_amdgcn_cvt_pkrtz(a, a);
}
static __device__ __forceinline__ unsigned short f2h(float x) {
  union { __fp16 h; unsigned short u; } c; c.h = (__fp16)x; return c.u;
}

#define LOADH8(dst, ptr) { \
  uint4 _a = *(const uint4*)(ptr); uint4 _b = *(const uint4*)((ptr)+8); U32H _t; \
  _t.u=_a.x; dst[0]=_t.h; _t.u=_a.y; dst[1]=_t.h; _t.u=_a.z; dst[2]=_t.h; _t.u=_a.w; dst[3]=_t.h; \
  _t.u=_b.x; dst[4]=_t.h; _t.u=_b.y; dst[5]=_t.h; _t.u=_b.z; dst[6]=_t.h; _t.u=_b.w; dst[7]=_t.h; }

// ---- k0: fold proj into fusion weight (fp16 B^T [64][800], kk = t*32+c); cast w1/w2 --
__global__ __launch_bounds__(256) void k_combine(
    const float* __restrict__ proj_w, const float* __restrict__ proj_b,
    const float* __restrict__ fw, const float* __restrict__ fb,
    const float* __restrict__ w1, const float* __restrict__ w2,
    unsigned short* __restrict__ wctT, float* __restrict__ bc,
    unsigned short* __restrict__ w1h, unsigned short* __restrict__ w2h)
{
  if (blockIdx.x == 200) {
    int o = threadIdx.x;
    if (o < 64) {
      float acc = proj_b[o];
      for (int m = 0; m < 64; ++m) acc = fmaf(proj_w[o*64+m], fb[m], acc);
      bc[o] = acc;
    }
    return;
  }
  if (blockIdx.x == 201) {
    for (int i = threadIdx.x; i < 8192; i += 256) w1h[i] = f2h(w1[i]);
    return;
  }
  if (blockIdx.x == 202) {
    for (int i = threadIdx.x; i < 8192; i += 256) w2h[i] = f2h(w2[i]);
    return;
  }
  int gid = blockIdx.x * 256 + threadIdx.x;   // 0..51199 = o*800 + kk
  int o  = gid / 800;
  int kk = gid - o * 800;
  int c  = kk & 31;        // de-interleaved channel (nh*16+d)
  int t  = kk >> 5;        // window position 0..24
  int in = c * 25 + t;     // fusion weight flat index
  float acc = 0.f;
  for (int m = 0; m < 64; ++m) acc = fmaf(proj_w[o*64+m], fw[m*800+in], acc);
  wctT[gid] = f2h(acc);
}

// ---- k1: LayerNorm + QKV, fp16 out, de-interleaved (c' = nh*16 + d); 3-way split ----
__global__ __launch_bounds__(128) void k_ln_qkv(
    const float* __restrict__ x, const float* __restrict__ qkv_w,
    const float* __restrict__ qkv_b, const float* __restrict__ n1w,
    const float* __restrict__ n1b, unsigned short* __restrict__ qo,
    unsigned short* __restrict__ ko, unsigned short* __restrict__ vo)
{
  __shared__ float sW[32*32];
  __shared__ float sB[32];
  __shared__ float sNw[32], sNb[32];
  int p = blockIdx.y;                         // 0=q 1=k 2=v
  for (int i = threadIdx.x; i < 32*32; i += 128) sW[i] = qkv_w[p*1024 + i];
  if (threadIdx.x < 32) {
    sB[threadIdx.x]  = qkv_b[p*32 + threadIdx.x];
    sNw[threadIdx.x] = n1w[threadIdx.x];
    sNb[threadIdx.x] = n1b[threadIdx.x];
  }
  __syncthreads();
  int gid = blockIdx.x * 128 + threadIdx.x;   // 0..BL-1
  int b = gid >> 14, l = gid & (LL - 1);
  const float* xp = x + (size_t)b * 32 * LL + l;
  float xv[32];
  float mean = 0.f;
  #pragma unroll
  for (int c = 0; c < 32; ++c) { xv[c] = xp[(size_t)c * LL]; mean += xv[c]; }
  mean *= 0.03125f;
  float var = 0.f;
  #pragma unroll
  for (int c = 0; c < 32; ++c) { float d = xv[c] - mean; var = fmaf(d, d, var); }
  float rs = rsqrtf(var * 0.03125f + 1e-5f);
  #pragma unroll
  for (int c = 0; c < 32; ++c) xv[c] = (xv[c] - mean) * rs * sNw[c] + sNb[c];
  float ao[32];
  #pragma unroll
  for (int o = 0; o < 32; ++o) {
    const float* wr = &sW[o * 32];
    float acc = sB[o];
    #pragma unroll
    for (int c = 0; c < 32; ++c) acc = fmaf(xv[c], wr[c], acc);
    ao[(o & 1) * 16 + (o >> 1)] = acc;        // de-interleave heads
  }
  unsigned short* op = (p == 0 ? qo : p == 1 ? ko : vo) + (size_t)gid * 32;
  #pragma unroll
  for (int e = 0; e < 4; ++e) {
    uint4 pk4;
    pk4.x = pkh2(ao[e*8+0], ao[e*8+1]);
    pk4.y = pkh2(ao[e*8+2], ao[e*8+3]);
    pk4.z = pkh2(ao[e*8+4], ao[e*8+5]);
    pk4.w = pkh2(ao[e*8+6], ao[e*8+7]);
    *(uint4*)(op + e*8) = pk4;
  }
}

// ---- k2: tiled windowed attention (fused QK-exp-PV, tq-QUAD, fp16 PV) + MFMA f16 ----
// Block = 4x8 = 32 locations, 256 threads (4 waves). 2 compute + 2 MFMA phases.
#define TH 4
#define TW 8
#define NPOS 96   // 8x12 halo
#define KVSTR 24  // per-head fp16 row stride in ushorts (48B; 16 data + pad)
#define OSTRU 524 // sO row stride (ushorts): 512 kk + 12 pad

__global__ __launch_bounds__(256, 3) void k_attn(
    const unsigned short* __restrict__ qi, const unsigned short* __restrict__ ki,
    const unsigned short* __restrict__ vi, const float* __restrict__ rel_table,
    const unsigned short* __restrict__ wctT, const float* __restrict__ bc,
    float* __restrict__ y2)
{
  __shared__ __align__(16) unsigned short sQ[192*KVSTR]; // 9216 B  ([nh*96+pos][16+pad])
  __shared__ __align__(16) unsigned short sK[192*KVSTR]; // 9216 B
  __shared__ __align__(16) unsigned short sV[192*KVSTR]; // 9216 B
  __shared__ __align__(16) unsigned short sO[32*OSTRU];  // 33536 B
  __shared__ float sRT[162];
  __shared__ float sPar[NPOS];
  // total ~48.8 KB -> 3 blocks/CU

  int tid = threadIdx.x;
  int lane = tid & 63, wv = tid >> 6;
  int b  = blockIdx.z;
  int h0 = blockIdx.y * TH, w0 = blockIdx.x * TW;

  for (int i = tid; i < 162; i += 256) sRT[i] = rel_table[i];
  if (tid < NPOS) {
    int ph = tid / 12, pw = tid - ph * 12;
    int h2v = h0 + ph - 2, w2v = w0 + pw - 2;
    bool valid = ((unsigned)h2v < HH) && ((unsigned)w2v < WW);
    sPar[tid] = (valid && (((h2v + w2v) & 1) == 1)) ? 1.f : 0.f;
  }
  // halo staging: 3 arrays x 96 pos x 2 nh x 2 half-chunks(16B) = 1152 units
  for (int idx = tid; idx < 1152; idx += 256) {
    int arr = idx / 384;                  // 0=K, 1=V, 2=Q
    int rem = idx - arr * 384;
    int pos = rem >> 2, q4 = rem & 3;
    int nh = q4 >> 1, half = q4 & 1;
    int ph = pos / 12, pw = pos - ph * 12;
    int h2v = h0 + ph - 2, w2v = w0 + pw - 2;
    uint4 val = make_uint4(0u, 0u, 0u, 0u);
    if (((unsigned)h2v < HH) && ((unsigned)w2v < WW)) {
      const unsigned short* src = (arr == 0 ? ki : arr == 1 ? vi : qi)
                       + ((size_t)((b << 14) + (h2v << 7) + w2v)) * 32 + nh * 16 + half * 8;
      val = *(const uint4*)src;
    }
    unsigned short* dp = (arr == 0 ? sK : arr == 1 ? sV : sQ)
                       + (nh * 96 + pos) * KVSTR + half * 8;
    *(uint4*)dp = val;
  }
  __syncthreads();

  f32x4 acc[2] = {{0.f,0.f,0.f,0.f},{0.f,0.f,0.f,0.f}};
  int ocol = wv * 16 + (lane & 15);

  for (int it = 0; it < 2; ++it) {
    int g = wv * 2 + (lane >> 5);             // 0..7, half-wave uniform
    int qd = it * 4 + (g >> 1);               // quad index 0..7
    int nh = g & 1;
    int nhb = nh * 96;
    if (qd < 7) {
      int nrr = (qd < 6) ? 4 : 1;             // valid rows in quad (tq<=24)
      int loc = lane & 31;
      int ly = loc >> 3, lx = loc & 7;
      int posb = ly * 12 + lx;
      int tqb = 4 * qd;
      int tq0 = tqb, tq1 = tqb+1, tq2 = tqb+2, tq3 = tqb+3;
      int iq0 = tq0/5, jq0 = tq0 - iq0*5;
      int iq1 = tq1/5, jq1 = tq1 - iq1*5;
      int iq2 = tq2/5, jq2 = tq2 - iq2*5;
      int iq3 = tq3/5, jq3 = tq3 - iq3*5;
      int pq0 = posb + iq0*12 + jq0; pq0 = pq0 > 95 ? 95 : pq0;
      int pq1 = posb + iq1*12 + jq1; pq1 = pq1 > 95 ? 95 : pq1;
      int pq2 = posb + iq2*12 + jq2; pq2 = pq2 > 95 ? 95 : pq2;
      int pq3 = posb + iq3*12 + jq3; pq3 = pq3 > 95 ? 95 : pq3;
      float parq0 = sPar[pq0], parq1 = sPar[pq1], parq2 = sPar[pq2], parq3 = sPar[pq3];
      h2 q0[8], q1[8], q2[8], q3[8];
      LOADH8(q0, &sQ[(nhb+pq0)*KVSTR]);
      LOADH8(q1, &sQ[(nhb+pq1)*KVSTR]);
      LOADH8(q2, &sQ[(nhb+pq2)*KVSTR]);
      LOADH8(q3, &sQ[(nhb+pq3)*KVSTR]);
      float s0 = 0.f, s1 = 0.f, s2 = 0.f, s3 = 0.f;
      h2 oo0[8], oo1[8], oo2[8], oo3[8];
      #pragma unroll
      for (int e = 0; e < 8; ++e) {
        oo0[e] = (h2)(__fp16)0.f; oo1[e] = (h2)(__fp16)0.f;
        oo2[e] = (h2)(__fp16)0.f; oo3[e] = (h2)(__fp16)0.f;
      }
      #pragma unroll 1
      for (int ik = 0; ik < 5; ++ik) {
        int rb0 = ((iq0-ik+4)*9 + jq0 + 4)*2 + nh;
        int rb1 = ((iq1-ik+4)*9 + jq1 + 4)*2 + nh;
        int rb2 = ((iq2-ik+4)*9 + jq2 + 4)*2 + nh;
        int rb3 = ((iq3-ik+4)*9 + jq3 + 4)*2 + nh;
        #pragma unroll
        for (int jk = 0; jk < 5; ++jk) {
          int pk = posb + ik*12 + jk;
          h2 kh[8];
          LOADH8(kh, &sK[(nhb+pk)*KVSTR]);
          float park = sPar[pk];
          float mk = (park == 1.f) ? 0.f : -100.f;
          float a0 = 0.f, a1 = 0.f, a2 = 0.f, a3 = 0.f;
          #pragma unroll
          for (int u = 0; u < 8; ++u) {
            a0 = fdot2(q0[u], kh[u], a0);
            a1 = fdot2(q1[u], kh[u], a1);
            a2 = fdot2(q2[u], kh[u], a2);
            a3 = fdot2(q3[u], kh[u], a3);
          }
          int i0 = rb0 - 2*jk; i0 = i0 > 161 ? 161 : i0;
          int i1 = rb1 - 2*jk; i1 = i1 > 161 ? 161 : i1;
          int i2 = rb2 - 2*jk; i2 = i2 > 161 ? 161 : i2;
          int i3 = rb3 - 2*jk; i3 = i3 > 161 ? 161 : i3;
          float e0 = __expf(fmaf(parq0, mk, fmaf(a0, 0.25f, sRT[i0])));
          float e1 = __expf(fmaf(parq1, mk, fmaf(a1, 0.25f, sRT[i1])));
          float e2 = __expf(fmaf(parq2, mk, fmaf(a2, 0.25f, sRT[i2])));
          float e3 = __expf(fmaf(parq3, mk, fmaf(a3, 0.25f, sRT[i3])));
          s0 += e0; s1 += e1; s2 += e2; s3 += e3;
          h2 e0h = bcasth(e0), e1h = bcasth(e1), e2h = bcasth(e2), e3h = bcasth(e3);
          h2 vh[8];
          LOADH8(vh, &sV[(nhb+pk)*KVSTR]);
          #pragma unroll
          for (int u = 0; u < 8; ++u) {
            oo0[u] = e0h * vh[u] + oo0[u];
            oo1[u] = e1h * vh[u] + oo1[u];
            oo2[u] = e2h * vh[u] + oo2[u];
            oo3[u] = e3h * vh[u] + oo3[u];
          }
        }
      }
      // write valid rows to sO (fp16), kl = (tq - it*16)*32 + nh*16
      #define WRITE_ROW(OO, SS, TQ) { \
        h2 ih = bcasth(1.f / (SS)); \
        int kl = ((TQ) - it*16) * 32 + nh * 16; \
        union { h2 h[8]; uint4 u4[2]; } R; \
        _Pragma("unroll") \
        for (int u = 0; u < 8; ++u) R.h[u] = OO[u] * ih; \
        *(uint4*)&sO[loc*OSTRU + kl] = R.u4[0]; \
        *(uint4*)&sO[loc*OSTRU + kl + 8] = R.u4[1]; }
      WRITE_ROW(oo0, s0, tq0);
      if (1 < nrr) WRITE_ROW(oo1, s1, tq1);
      if (2 < nrr) WRITE_ROW(oo2, s2, tq2);
      if (3 < nrr) WRITE_ROW(oo3, s3, tq3);
      #undef WRITE_ROW
    }
    __syncthreads();
    // MFMA phase: kt in [it*16, it*16+ktn)
    int ktn = it ? 9 : 16;
    const unsigned short* bcol = wctT + (size_t)ocol * 800 + it * 512 + (lane >> 4) * 8;
    for (int kt = 0; kt < ktn; ++kt) {
      h8 bfrag = *(const h8*)(bcol + kt * 32);
      #pragma unroll
      for (int mt = 0; mt < 2; ++mt) {
        h8 afrag = *(const h8*)&sO[(mt*16 + (lane & 15))*OSTRU + kt*32 + (lane >> 4)*8];
        acc[mt] = __builtin_amdgcn_mfma_f32_16x16x32_f16(afrag, bfrag, acc[mt], 0, 0, 0);
      }
    }
    __syncthreads();
  }
  // epilogue: y2[loc][o] = acc + bc[o]
  float bco = bc[ocol];
  #pragma unroll
  for (int mt = 0; mt < 2; ++mt) {
    #pragma unroll
    for (int r2 = 0; r2 < 4; ++r2) {
      int loc = mt * 16 + (lane >> 4) * 4 + r2;
      int ly = loc >> 3, lx = loc & 7;
      int gid = (b << 14) + ((h0 + ly) << 7) + (w0 + lx);
      y2[(size_t)gid * 64 + ocol] = acc[mt][r2] + bco;
    }
  }
}

// ---- k3: LN + MLP via MFMA f16 (GELU exact) + residual + transpose store ------------
__global__ __launch_bounds__(256) void k_mlp(
    const float* __restrict__ y2, const float* __restrict__ n2w,
    const float* __restrict__ n2b, const unsigned short* __restrict__ w1h,
    const float* __restrict__ b1, const unsigned short* __restrict__ w2h,
    const float* __restrict__ b2, float* __restrict__ out)
{
  __shared__ __align__(16) unsigned short sA[64*72];   // 9216 B  (LN'd input, fp16)
  __shared__ __align__(16) unsigned short sH[64*136];  // 17408 B (GELU output, fp16)
  int tid = threadIdx.x;
  int lane = tid & 63, wv = tid >> 6;
  int m0 = blockIdx.x * 64;
  // ---- LN: 4 threads per row
  {
    int r = tid >> 2, qd = tid & 3;
    const float* yp = y2 + (size_t)(m0 + r) * 64 + qd * 16;
    float xv[16];
    float s = 0.f;
    #pragma unroll
    for (int e = 0; e < 4; ++e) {
      float4 t4 = *(const float4*)(yp + e*4);
      xv[4*e] = t4.x; xv[4*e+1] = t4.y; xv[4*e+2] = t4.z; xv[4*e+3] = t4.w;
      s += t4.x + t4.y + t4.z + t4.w;
    }
    s += __shfl_xor(s, 1);
    s += __shfl_xor(s, 2);
    float mean = s * (1.f/64.f);
    float v = 0.f;
    #pragma unroll
    for (int e = 0; e < 16; ++e) { float d = xv[e] - mean; v = fmaf(d, d, v); }
    v += __shfl_xor(v, 1);
    v += __shfl_xor(v, 2);
    float rs = rsqrtf(v * (1.f/64.f) + 1e-5f);
    #pragma unroll
    for (int u = 0; u < 8; ++u) {
      int c0 = qd*16 + 2*u;
      float h0v = (xv[2*u]   - mean) * rs * n2w[c0]   + n2b[c0];
      float h1v = (xv[2*u+1] - mean) * rs * n2w[c0+1] + n2b[c0+1];
      *(unsigned*)&sA[r*72 + c0] = pkh2(h0v, h1v);
    }
  }
  __syncthreads();
  // ---- GEMM1: [64x64] x W1^T -> [64x128], n-slice 32 per wave
  f32x4 acc1[4][2];
  #pragma unroll
  for (int mt = 0; mt < 4; ++mt)
    #pragma unroll
    for (int nt = 0; nt < 2; ++nt) acc1[mt][nt] = (f32x4){0.f,0.f,0.f,0.f};
  #pragma unroll
  for (int kt = 0; kt < 2; ++kt) {
    #pragma unroll
    for (int nt = 0; nt < 2; ++nt) {
      int ncol = wv*32 + nt*16 + (lane & 15);
      h8 bfrag = *(const h8*)(w1h + ncol*64 + kt*32 + (lane >> 4)*8);
      #pragma unroll
      for (int mt = 0; mt < 4; ++mt) {
        h8 afrag = *(const h8*)&sA[(mt*16 + (lane & 15))*72 + kt*32 + (lane >> 4)*8];
        acc1[mt][nt] = __builtin_amdgcn_mfma_f32_16x16x32_f16(afrag, bfrag, acc1[mt][nt], 0, 0, 0);
      }
    }
  }
  // ---- bias + exact GELU -> sH (fp16)
  #pragma unroll
  for (int nt = 0; nt < 2; ++nt) {
    int ncol = wv*32 + nt*16 + (lane & 15);
    float b1v = b1[ncol];
    #pragma unroll
    for (int mt = 0; mt < 4; ++mt) {
      #pragma unroll
      for (int r2 = 0; r2 < 4; ++r2) {
        int mrow = mt*16 + (lane >> 4)*4 + r2;
        float h = acc1[mt][nt][r2] + b1v;
        float g = 0.5f * h * (1.f + erff(h * 0.70710678118f));
        sH[mrow*136 + ncol] = f2h(g);
      }
    }
  }
  __syncthreads();
  // ---- GEMM2: [64x128] x W2^T -> [64x64], n-slice 16 per wave
  f32x4 acc2[4];
  #pragma unroll
  for (int mt = 0; mt < 4; ++mt) acc2[mt] = (f32x4){0.f,0.f,0.f,0.f};
  int ocol = wv*16 + (lane & 15);
  #pragma unroll
  for (int kt = 0; kt < 4; ++kt) {
    h8 bfrag = *(const h8*)(w2h + ocol*128 + kt*32 + (lane >> 4)*8);
    #pragma unroll
    for (int mt = 0; mt < 4; ++mt) {
      h8 afrag = *(const h8*)&sH[(mt*16 + (lane & 15))*136 + kt*32 + (lane >> 4)*8];
      acc2[mt] = __builtin_amdgcn_mfma_f32_16x16x32_f16(afrag, bfrag, acc2[mt], 0, 0, 0);
    }
  }
  // ---- residual + bias + transpose store
  float b2v = b2[ocol];
  int bb = m0 >> 14;
  #pragma unroll
  for (int mt = 0; mt < 4; ++mt) {
    int mrow = mt*16 + (lane >> 4)*4;
    int l = m0 + mrow;
    const float* yp = y2 + (size_t)l * 64 + ocol;
    float4 o4;
    o4.x = yp[0]   + acc2[mt][0] + b2v;
    o4.y = yp[64]  + acc2[mt][1] + b2v;
    o4.z = yp[128] + acc2[mt][2] + b2v;
    o4.w = yp[192] + acc2[mt][3] + b2v;
    *(float4*)&out[(size_t)bb * 64 * LL + (size_t)ocol * LL + (l - (bb << 14))] = o4;
  }
}

extern "C" void kernel_launch(void* const* d_in, const int* in_sizes, int n_in,
                              void* d_out, int out_size, void* d_ws, size_t ws_size,
                              hipStream_t stream) {
  const float* x         = (const float*)d_in[0];
  const float* qkv_w     = (const float*)d_in[1];
  const float* qkv_b     = (const float*)d_in[2];
  const float* rel_table = (const float*)d_in[3];
  const float* n1w       = (const float*)d_in[4];
  const float* n1b       = (const float*)d_in[5];
  const float* n2w       = (const float*)d_in[6];
  const float* n2b       = (const float*)d_in[7];
  const float* proj_w    = (const float*)d_in[8];
  const float* proj_b    = (const float*)d_in[9];
  const float* fw        = (const float*)d_in[10];
  const float* fb        = (const float*)d_in[11];
  const float* w1        = (const float*)d_in[12];
  const float* b1        = (const float*)d_in[13];
  const float* w2        = (const float*)d_in[14];
  const float* b2        = (const float*)d_in[15];

  char* ws = (char*)d_ws;
  unsigned short* q    = (unsigned short*)(ws);                    // BL*32 fp16 = 2MB
  unsigned short* k    = (unsigned short*)(ws + 2097152);          // 2MB
  unsigned short* v    = (unsigned short*)(ws + 4194304);          // 2MB
  float*          y2   = (float*)(ws + 6291456);                   // BL*64 f32 = 8MB
  unsigned short* wctT = (unsigned short*)(ws + 14680064);         // 64*800 fp16
  float*          bc   = (float*)(ws + 14782464);                  // 64 f32
  unsigned short* w1h  = (unsigned short*)(ws + 14782720);         // 8192 fp16
  unsigned short* w2h  = (unsigned short*)(ws + 14799104);         // 8192 fp16
  float* out = (float*)d_out;

  k_combine<<<203, 256, 0, stream>>>(proj_w, proj_b, fw, fb, w1, w2, wctT, bc, w1h, w2h);
  k_ln_qkv<<<dim3(BL/128, 3), 128, 0, stream>>>(x, qkv_w, qkv_b, n1w, n1b, q, k, v);
  k_attn<<<dim3(WW/TW, HH/TH, 2), 256, 0, stream>>>(q, k, v, rel_table, wctT, bc, y2);
  k_mlp<<<BL/64, 256, 0, stream>>>(y2, n2w, n2b, w1h, b1, w2h, b2, out);
}